// Round 5
// baseline (1053.248 us; speedup 1.0000x reference)
//
#include <hip/hip_runtime.h>
#include <math.h>

#define B_ 4
#define S_ 2048
#define D_ 1024
#define F_ 4096
#define E_ 4
#define T_ (B_*S_)        // 8192 tokens
#define PCAP_ 8704        // max padded rows: 8192 + 4*127 rounded to 128
#define GCAP_ (PCAP_/16)  // 544 row-groups

typedef unsigned short ushort_t;
typedef __attribute__((ext_vector_type(8))) short short8;
typedef __attribute__((ext_vector_type(4))) float f32x4;

__device__ __forceinline__ ushort_t f2bf_rne(float f) {
    unsigned u = __float_as_uint(f);
    unsigned r = 0x7FFFu + ((u >> 16) & 1u);
    u += r;
    return (ushort_t)(u >> 16);
}
__device__ __forceinline__ float bf2f(ushort_t h) {
    return __uint_as_float(((unsigned)h) << 16);
}
__device__ __forceinline__ void split_bf16(float f, ushort_t &hi, ushort_t &lo) {
    hi = f2bf_rne(f);
    lo = f2bf_rne(f - bf2f(hi));
}

__device__ __forceinline__ void gload16(const void* g, void* l) {
    __builtin_amdgcn_global_load_lds(
        (const __attribute__((address_space(1))) unsigned int*)g,
        (__attribute__((address_space(3))) unsigned int*)l, 16, 0, 0);
}

// ---------------- routing ----------------

__global__ void k_router(const float* __restrict__ x, const float* __restrict__ rw,
                         float* __restrict__ r, int* __restrict__ counts) {
    if (blockIdx.x == 0 && threadIdx.x < E_) counts[threadIdx.x] = 0;
    int wid = blockIdx.x * 4 + (threadIdx.x >> 6);
    int lane = threadIdx.x & 63;
    const float* xr = x + (size_t)wid * D_;
    float a0 = 0.f, a1 = 0.f, a2 = 0.f, a3 = 0.f;
    for (int i = lane; i < D_; i += 64) {
        float xv = xr[i];
        float4 w = reinterpret_cast<const float4*>(rw)[i];
        a0 += xv * w.x; a1 += xv * w.y; a2 += xv * w.z; a3 += xv * w.w;
    }
    for (int off = 32; off; off >>= 1) {
        a0 += __shfl_down(a0, off, 64);
        a1 += __shfl_down(a1, off, 64);
        a2 += __shfl_down(a2, off, 64);
        a3 += __shfl_down(a3, off, 64);
    }
    if (lane == 0) {
        float4 v; v.x = a0; v.y = a1; v.z = a2; v.w = a3;
        reinterpret_cast<float4*>(r)[wid] = v;
    }
}

__global__ void k_scan(float* __restrict__ r) {
    int b = blockIdx.x >> 2, e = blockIdx.x & 3;
    int lane = threadIdx.x;
    float carry = 0.f;
    for (int c = 0; c < S_ / 64; ++c) {
        int s = c * 64 + lane;
        float* p = r + ((size_t)(b * S_ + s)) * E_ + e;
        float v = *p;
        #pragma unroll
        for (int off = 1; off < 64; off <<= 1) {
            float u = __shfl_up(v, off, 64);
            if (lane >= off) v += u;
        }
        v += carry;
        *p = v;
        carry = __shfl(v, 63, 64);
    }
}

__global__ void k_route(const float* __restrict__ r, float* __restrict__ gate,
                        int* __restrict__ list, int* __restrict__ counts) {
    int t = blockIdx.x * blockDim.x + threadIdx.x;
    if (t >= T_) return;
    int s = t & (S_ - 1);
    float4 l4 = reinterpret_cast<const float4*>(r)[t];
    float inv = 1.f / (float)(s + 1);
    float l[4] = { l4.x * inv, l4.y * inv, l4.z * inv, l4.w * inv };
    int best = 0; float m = l[0];
    #pragma unroll
    for (int e = 1; e < 4; ++e) if (l[e] > m) { m = l[e]; best = e; }
    float sum = 0.f;
    #pragma unroll
    for (int e = 0; e < 4; ++e) sum += expf(l[e] - m);
    gate[t] = 1.f / sum;
    int pos = atomicAdd(&counts[best], 1);
    list[best * T_ + pos] = t;
}

__global__ void k_offs(const int* __restrict__ counts, int* __restrict__ offs,
                       int* __restrict__ pbase) {
    if (threadIdx.x == 0) {
        int a = 0, p = 0;
        pbase[0] = 0;
        for (int e = 0; e < E_; ++e) {
            offs[e] = a; a += counts[e];
            p += (counts[e] + 127) & ~127;
            pbase[e + 1] = p;
        }
    }
}

// ---------------- gather x into padded expert order, frag-tiled hi/lo ----------------
__global__ __launch_bounds__(256)
void k_gather(const float* __restrict__ x, const int* __restrict__ list,
              const int* __restrict__ counts, const int* __restrict__ pbase,
              ushort_t* __restrict__ Xh, ushort_t* __restrict__ Xl)
{
    constexpr int KB = D_ / 32;
    const int g = blockIdx.x;
    const int r15 = threadIdx.x & 15;
    const int kq = threadIdx.x >> 4;
    const int v = g * 16 + r15;
    int e = 0;
    #pragma unroll
    for (int i = 0; i < E_; ++i) if (v >= pbase[i + 1]) e = i + 1;
    int token = -1;
    if (e < E_) {
        int local = v - pbase[e];
        if (local < counts[e]) token = list[e * T_ + local];
    }
    const float* xr = x + (size_t)(token >= 0 ? token : 0) * D_;
    #pragma unroll
    for (int c8 = 0; c8 < 8; ++c8) {
        const int k = kq * 64 + c8 * 8;
        float vv[8];
        if (token >= 0) {
            float4 u0 = *reinterpret_cast<const float4*>(xr + k);
            float4 u1 = *reinterpret_cast<const float4*>(xr + k + 4);
            vv[0]=u0.x; vv[1]=u0.y; vv[2]=u0.z; vv[3]=u0.w;
            vv[4]=u1.x; vv[5]=u1.y; vv[6]=u1.z; vv[7]=u1.w;
        } else {
            #pragma unroll
            for (int j = 0; j < 8; ++j) vv[j] = 0.f;
        }
        unsigned hw[4], lw[4];
        #pragma unroll
        for (int j = 0; j < 4; ++j) {
            ushort_t h0, l0, h1, l1;
            split_bf16(vv[2*j], h0, l0);
            split_bf16(vv[2*j+1], h1, l1);
            hw[j] = (unsigned)h0 | ((unsigned)h1 << 16);
            lw[j] = (unsigned)l0 | ((unsigned)l1 << 16);
        }
        size_t off = (((size_t)g * KB + (k >> 5)) * 64 + ((k >> 3) & 3) * 16 + r15) * 8;
        *reinterpret_cast<uint4*>(Xh + off) = make_uint4(hw[0], hw[1], hw[2], hw[3]);
        *reinterpret_cast<uint4*>(Xl + off) = make_uint4(lw[0], lw[1], lw[2], lw[3]);
    }
}

// ---------------- weight conversion to frag-order planes ----------------
__global__ __launch_bounds__(256)
void k_convert_w(const float* __restrict__ W, ushort_t* __restrict__ Ph,
                 ushort_t* __restrict__ Pl, int K, int N) {
    const int e = blockIdx.z;
    const int n0 = blockIdx.x * 128;
    const int k0 = blockIdx.y * 32;
    const int kb = blockIdx.y;
    const int NT = N >> 4, KB = K >> 5;
    __shared__ float lf[32 * 128];
    const float* We = W + (size_t)e * K * N;
    const int tid = threadIdx.x;
    #pragma unroll
    for (int i = 0; i < 4; ++i) {
        int q = i * 256 + tid;
        int k = q >> 5, c4 = q & 31;
        float4 v = *reinterpret_cast<const float4*>(We + (size_t)(k0 + k) * N + n0 + c4 * 4);
        *reinterpret_cast<float4*>(lf + k * 128 + c4 * 4) = v;
    }
    __syncthreads();
    #pragma unroll
    for (int p = 0; p < 2; ++p) {
        int q = p * 256 + tid;
        int n = q & 127, kg = q >> 7;
        unsigned hw[4], lw[4];
        #pragma unroll
        for (int j = 0; j < 8; j += 2) {
            float f0 = lf[(kg * 8 + j) * 128 + n];
            float f1 = lf[(kg * 8 + j + 1) * 128 + n];
            ushort_t h0, l0, h1, l1;
            split_bf16(f0, h0, l0);
            split_bf16(f1, h1, l1);
            hw[j >> 1] = (unsigned)h0 | ((unsigned)h1 << 16);
            lw[j >> 1] = (unsigned)l0 | ((unsigned)l1 << 16);
        }
        size_t off = ((((size_t)e * NT + ((n0 + n) >> 4)) * KB + kb) * 64
                      + (kg * 16 + (n & 15))) * 8;
        *reinterpret_cast<uint4*>(Ph + off) = make_uint4(hw[0], hw[1], hw[2], hw[3]);
        *reinterpret_cast<uint4*>(Pl + off) = make_uint4(lw[0], lw[1], lw[2], lw[3]);
    }
}

// ---------------- main grouped GEMMs: counted-vmcnt 2-deep pipeline + XCD swizzle ----
// MODE 0: h(frag-order planes) = gelu(Xg @ w1 + b1)   K=1024, N=4096
// MODE 1: out(scatter,f32)     = gate*(h @ w2 + b2)   K=4096, N=1024
// Tile 128x128, BK=32, 4 waves (2x2), 64x64/wave, split-bf16 3-pass MFMA.
// Per iter: ds_read -> lgkmcnt(0) -> s_barrier -> issue t+2 -> MFMA -> vmcnt(8)
// -> s_barrier. Loads stay in flight across barriers (never drain to 0 in-loop).
template<int MODE>
__global__ __launch_bounds__(256)
void k_g5(const ushort_t* __restrict__ Ah, const ushort_t* __restrict__ Al,
          const ushort_t* __restrict__ Bh, const ushort_t* __restrict__ Bl,
          const float* __restrict__ bias, float* __restrict__ outF,
          ushort_t* __restrict__ outHh, ushort_t* __restrict__ outHl,
          const int* __restrict__ list, const int* __restrict__ counts,
          const int* __restrict__ pbase, const float* __restrict__ gate)
{
    constexpr int K  = (MODE == 0) ? D_ : F_;
    constexpr int N  = (MODE == 0) ? F_ : D_;
    constexpr int KB = K / 32;
    constexpr int NT = N / 16;
    constexpr int KBH = F_ / 32;
    constexpr int NX = T_ / 128;          // 64 m-blocks (worst case)
    constexpr int NY = N / 128;
    constexpr int NWG = NX * NY * E_;     // 8192 / 2048, both %8==0

    // XCD-aware bijective swizzle: contiguous orig-chunks per XCD (T1).
    const int bid = blockIdx.x;
    const int orig = (bid & 7) * (NWG >> 3) + (bid >> 3);
    const int e = orig / (NX * NY);
    const int rem = orig - e * (NX * NY);
    const int by = rem / NX;
    const int bx = rem - by * NX;

    const int cnt = counts[e];
    const int m0 = bx * 128;
    if (m0 >= cnt) return;
    const int n0 = by * 128;
    const int pb = pbase[e];
    const int tid = threadIdx.x, wid = tid >> 6, lane = tid & 63;
    const int l15 = lane & 15, lkg = lane >> 4;
    const int wr = wid >> 1, wc = wid & 1;
    const int G0 = (pb + m0) >> 4;

    // double-buffered: each buffer = Ah[8][512] @0, Al @4096, Bh @8192, Bl @12288
    __shared__ __align__(16) ushort_t lds[2][16384];

    const ushort_t* aph[2]; const ushort_t* apl[2];
    const ushort_t* bph[2]; const ushort_t* bpl[2];
    #pragma unroll
    for (int i = 0; i < 2; ++i) {
        const int c = wid * 2 + i;
        size_t ab = ((size_t)(G0 + c) * KB) * 512 + (size_t)lane * 8;
        size_t bb = (((size_t)e * NT + (n0 >> 4) + c) * KB) * 512 + (size_t)lane * 8;
        aph[i] = Ah + ab; apl[i] = Al + ab;
        bph[i] = Bh + bb; bpl[i] = Bl + bb;
    }

    f32x4 acc[4][4];
    #pragma unroll
    for (int i = 0; i < 4; ++i)
        #pragma unroll
        for (int j = 0; j < 4; ++j) acc[i][j] = (f32x4){0.f, 0.f, 0.f, 0.f};

    #define STAGE_(KBI, BUFI)                                              \
        {                                                                  \
            ushort_t* Lp = &lds[(BUFI)][0];                                \
            const size_t kk = (size_t)(KBI) * 512;                         \
            _Pragma("unroll")                                              \
            for (int i = 0; i < 2; ++i) {                                  \
                const int c = wid * 2 + i;                                 \
                gload16(aph[i] + kk, Lp + c * 512);                        \
                gload16(apl[i] + kk, Lp + 4096 + c * 512);                 \
                gload16(bph[i] + kk, Lp + 8192 + c * 512);                 \
                gload16(bpl[i] + kk, Lp + 12288 + c * 512);                \
            }                                                              \
        }

    // prologue: tiles 0 and 1 in flight; wait tile 0 landed (8 of 16 left)
    STAGE_(0, 0);
    STAGE_(1, 1);
    asm volatile("s_waitcnt vmcnt(8)" ::: "memory");
    __builtin_amdgcn_sched_barrier(0);
    __builtin_amdgcn_s_barrier();

    int cur = 0;
    for (int kb = 0; kb < KB; ++kb) {
        // ---- fragments from buf[cur] (tile kb, guaranteed landed) ----
        const ushort_t* L = &lds[cur][0];
        short8 ah[4], al[4], bh[4], bl[4];
        #pragma unroll
        for (int mi = 0; mi < 4; ++mi) {
            int rf = wr * 4 + mi;
            ah[mi] = *reinterpret_cast<const short8*>(&L[rf * 512 + lane * 8]);
            al[mi] = *reinterpret_cast<const short8*>(&L[4096 + rf * 512 + lane * 8]);
        }
        #pragma unroll
        for (int ni = 0; ni < 4; ++ni) {
            int nt = wc * 4 + ni;
            bh[ni] = *reinterpret_cast<const short8*>(&L[8192 + nt * 512 + lane * 8]);
            bl[ni] = *reinterpret_cast<const short8*>(&L[12288 + nt * 512 + lane * 8]);
        }
        // all reads in regs before we let anyone overwrite buf[cur]
        asm volatile("s_waitcnt lgkmcnt(0)" ::: "memory");
        __builtin_amdgcn_sched_barrier(0);
        __builtin_amdgcn_s_barrier();
        // ---- issue tile kb+2 into buf[cur] (now free) ----
        if (kb + 2 < KB) STAGE_(kb + 2, cur);
        // ---- compute ----
        __builtin_amdgcn_s_setprio(1);
        #pragma unroll
        for (int mi = 0; mi < 4; ++mi)
            #pragma unroll
            for (int ni = 0; ni < 4; ++ni) {
                acc[mi][ni] = __builtin_amdgcn_mfma_f32_16x16x32_bf16(ah[mi], bh[ni], acc[mi][ni], 0, 0, 0);
                acc[mi][ni] = __builtin_amdgcn_mfma_f32_16x16x32_bf16(ah[mi], bl[ni], acc[mi][ni], 0, 0, 0);
                acc[mi][ni] = __builtin_amdgcn_mfma_f32_16x16x32_bf16(al[mi], bh[ni], acc[mi][ni], 0, 0, 0);
            }
        __builtin_amdgcn_s_setprio(0);
        // ---- tile kb+1 must be visible to ALL waves before next iter reads it ----
        if (kb + 2 < KB) {
            asm volatile("s_waitcnt vmcnt(8)" ::: "memory");   // t+1's 8 landed (t+2's 8 may fly)
        } else {
            asm volatile("s_waitcnt vmcnt(0)" ::: "memory");   // tail: no new issue to count against
        }
        __builtin_amdgcn_sched_barrier(0);
        __builtin_amdgcn_s_barrier();
        cur ^= 1;
    }
    #undef STAGE_

    const float* be = bias + (size_t)e * N;
    if (MODE == 0) {
        #pragma unroll
        for (int mi = 0; mi < 4; ++mi) {
            const int g2 = G0 + wr * 4 + mi;
            #pragma unroll
            for (int rg = 0; rg < 4; ++rg) {
                const int r15o = lkg * 4 + rg;
                #pragma unroll
                for (int ni = 0; ni < 4; ++ni) {
                    const int f = n0 + wc * 64 + ni * 16 + l15;
                    float v = acc[mi][ni][rg] + be[f];
                    float u = 1.5957691216057308f * (v + 0.044715f * v * v * v);
                    v = v / (1.f + __expf(-u));
                    ushort_t h, l;
                    split_bf16(v, h, l);
                    size_t off = (((size_t)g2 * KBH + (f >> 5)) * 64
                                  + ((f >> 3) & 3) * 16 + r15o) * 8 + (f & 7);
                    outHh[off] = h;
                    outHl[off] = l;
                }
            }
        }
    } else {
        const int* lst = list + (size_t)e * T_;
        #pragma unroll
        for (int mi = 0; mi < 4; ++mi) {
            #pragma unroll
            for (int rg = 0; rg < 4; ++rg) {
                int rm = m0 + wr * 64 + mi * 16 + lkg * 4 + rg;
                if (rm >= cnt) continue;
                int t = lst[rm];
                float gv = gate[t];
                float* crow = outF + (size_t)t * (size_t)N;
                #pragma unroll
                for (int ni = 0; ni < 4; ++ni) {
                    int col = n0 + wc * 64 + ni * 16 + l15;
                    crow[col] = gv * (acc[mi][ni][rg] + be[col]);
                }
            }
        }
    }
}

// ---------------- tier-B fallback (round-2 proven path) ----------------

__global__ void k_convert_x(const float* __restrict__ x,
                            ushort_t* __restrict__ xh, ushort_t* __restrict__ xl) {
    size_t i = ((size_t)blockIdx.x * 256 + threadIdx.x) * 8;
    float4 a = *reinterpret_cast<const float4*>(x + i);
    float4 b = *reinterpret_cast<const float4*>(x + i + 4);
    float v[8] = { a.x, a.y, a.z, a.w, b.x, b.y, b.z, b.w };
    unsigned hw[4], lw[4];
    #pragma unroll
    for (int j = 0; j < 4; ++j) {
        ushort_t h0, l0, h1, l1;
        split_bf16(v[2*j], h0, l0);
        split_bf16(v[2*j+1], h1, l1);
        hw[j] = (unsigned)h0 | ((unsigned)h1 << 16);
        lw[j] = (unsigned)l0 | ((unsigned)l1 << 16);
    }
    *reinterpret_cast<uint4*>(xh + i) = make_uint4(hw[0], hw[1], hw[2], hw[3]);
    *reinterpret_cast<uint4*>(xl + i) = make_uint4(lw[0], lw[1], lw[2], lw[3]);
}

template<int MODE>
__global__ __launch_bounds__(256)
void k_gemm2(const ushort_t* __restrict__ Ah, const ushort_t* __restrict__ Al,
             const ushort_t* __restrict__ Bh, const ushort_t* __restrict__ Bl,
             const float* __restrict__ bias, float* __restrict__ outF,
             ushort_t* __restrict__ outHh, ushort_t* __restrict__ outHl,
             const int* __restrict__ list, const int* __restrict__ counts,
             const int* __restrict__ offs, const float* __restrict__ gate,
             int K, int N, int NT)
{
    const int e = blockIdx.z;
    const int cnt = counts[e];
    const int m0 = blockIdx.x * 128;
    if (m0 >= cnt) return;
    const int n0 = blockIdx.y * 128;
    const int hbase = offs[e];
    const int KB = K >> 5;
    const int tid = threadIdx.x, wid = tid >> 6, lane = tid & 63;
    const int l15 = lane & 15, lkg = lane >> 4;
    const int* lst = list + (size_t)e * T_;
    __shared__ __align__(16) ushort_t lds[16384];
    size_t a_rel[2], b_rel[2];
    #pragma unroll
    for (int i = 0; i < 2; ++i) {
        int rf = wid * 2 + i;
        int rm = m0 + rf * 16 + l15;
        int rr = rm < cnt ? rm : cnt - 1;
        size_t row = (MODE == 0) ? (size_t)lst[rr] : (size_t)(hbase + rr);
        a_rel[i] = row * (size_t)K + (size_t)lkg * 8;
        b_rel[i] = (((size_t)e * NT + (n0 >> 4) + rf) * (size_t)KB) * 512 + (size_t)lane * 8;
    }
    const int wr = wid >> 1, wc = wid & 1;
    f32x4 acc[4][4];
    #pragma unroll
    for (int i = 0; i < 4; ++i)
        #pragma unroll
        for (int j = 0; j < 4; ++j) acc[i][j] = (f32x4){0.f, 0.f, 0.f, 0.f};
    for (int kb = 0; kb < KB; ++kb) {
        __syncthreads();
        #pragma unroll
        for (int i = 0; i < 2; ++i) {
            int c = wid * 2 + i;
            gload16(Ah + a_rel[i] + (size_t)kb * 32, &lds[c * 512]);
            gload16(Al + a_rel[i] + (size_t)kb * 32, &lds[4096 + c * 512]);
            gload16(Bh + b_rel[i] + (size_t)kb * 512, &lds[8192 + c * 512]);
            gload16(Bl + b_rel[i] + (size_t)kb * 512, &lds[12288 + c * 512]);
        }
        __syncthreads();
        short8 ah[4], al[4], bh[4], bl[4];
        #pragma unroll
        for (int mi = 0; mi < 4; ++mi) {
            int rf = wr * 4 + mi;
            ah[mi] = *reinterpret_cast<const short8*>(&lds[rf * 512 + lane * 8]);
            al[mi] = *reinterpret_cast<const short8*>(&lds[4096 + rf * 512 + lane * 8]);
        }
        #pragma unroll
        for (int ni = 0; ni < 4; ++ni) {
            int nt = wc * 4 + ni;
            bh[ni] = *reinterpret_cast<const short8*>(&lds[8192 + nt * 512 + lane * 8]);
            bl[ni] = *reinterpret_cast<const short8*>(&lds[12288 + nt * 512 + lane * 8]);
        }
        #pragma unroll
        for (int mi = 0; mi < 4; ++mi)
            #pragma unroll
            for (int ni = 0; ni < 4; ++ni) {
                acc[mi][ni] = __builtin_amdgcn_mfma_f32_16x16x32_bf16(ah[mi], bh[ni], acc[mi][ni], 0, 0, 0);
                acc[mi][ni] = __builtin_amdgcn_mfma_f32_16x16x32_bf16(ah[mi], bl[ni], acc[mi][ni], 0, 0, 0);
                acc[mi][ni] = __builtin_amdgcn_mfma_f32_16x16x32_bf16(al[mi], bh[ni], acc[mi][ni], 0, 0, 0);
            }
    }
    const float* be = bias + (size_t)e * N;
    #pragma unroll
    for (int mi = 0; mi < 4; ++mi) {
        #pragma unroll
        for (int rg = 0; rg < 4; ++rg) {
            int rm = m0 + wr * 64 + mi * 16 + lkg * 4 + rg;
            if (rm >= cnt) continue;
            if (MODE == 0) {
                size_t rowb = (size_t)(hbase + rm) * (size_t)F_;
                #pragma unroll
                for (int ni = 0; ni < 4; ++ni) {
                    int col = n0 + wc * 64 + ni * 16 + l15;
                    float v = acc[mi][ni][rg] + be[col];
                    float u = 1.5957691216057308f * (v + 0.044715f * v * v * v);
                    v = v / (1.f + __expf(-u));
                    ushort_t h, l;
                    split_bf16(v, h, l);
                    outHh[rowb + col] = h;
                    outHl[rowb + col] = l;
                }
            } else {
                int t = lst[rm];
                float gv = gate[t];
                float* crow = outF + (size_t)t * (size_t)N;
                #pragma unroll
                for (int ni = 0; ni < 4; ++ni) {
                    int col = n0 + wc * 64 + ni * 16 + l15;
                    crow[col] = gv * (acc[mi][ni][rg] + be[col]);
                }
            }
        }
    }
}

// ---------------- launch ----------------

extern "C" void kernel_launch(void* const* d_in, const int* in_sizes, int n_in,
                              void* d_out, int out_size, void* d_ws, size_t ws_size,
                              hipStream_t stream) {
    const float* x   = (const float*)d_in[0];
    const float* rw  = (const float*)d_in[1];
    const float* w1  = (const float*)d_in[2];
    const float* b1  = (const float*)d_in[3];
    const float* w2  = (const float*)d_in[4];
    const float* b2  = (const float*)d_in[5];
    float* out = (float*)d_out;

    const size_t HCAP = (size_t)PCAP_ * F_;
    const size_t XCAP = (size_t)PCAP_ * D_;
    const size_t WCAP = (size_t)E_ * D_ * F_;
    const size_t misc = ((size_t)T_ * E_ + T_ + (size_t)E_ * T_) * 4 + 256;

    const size_t need_A = (2 * HCAP + 2 * XCAP + 2 * WCAP) * 2 + misc;   // ~246 MB
    const size_t hf = (size_t)T_ * F_;
    const size_t xd = (size_t)T_ * D_;
    const size_t need_B = (2 * hf + 2 * xd + 2 * WCAP) * 2 + misc;       // ~201 MB

    if (ws_size >= need_A) {
        ushort_t* hh  = (ushort_t*)d_ws;
        ushort_t* hl  = hh + HCAP;
        ushort_t* xh  = hl + HCAP;
        ushort_t* xl  = xh + XCAP;
        ushort_t* wph = xl + XCAP;
        ushort_t* wpl = wph + WCAP;
        float* r    = (float*)(wpl + WCAP);
        float* gate = r + (size_t)T_ * E_;
        int* list   = (int*)(gate + T_);
        int* counts = list + (size_t)E_ * T_;
        int* offs   = counts + E_;
        int* pbase  = offs + E_;

        k_router<<<T_ / 4, 256, 0, stream>>>(x, rw, r, counts);
        k_convert_w<<<dim3(F_ / 128, D_ / 32, E_), 256, 0, stream>>>(w1, wph, wpl, D_, F_);
        k_scan<<<B_ * E_, 64, 0, stream>>>(r);
        k_route<<<T_ / 256, 256, 0, stream>>>(r, gate, list, counts);
        k_offs<<<1, 64, 0, stream>>>(counts, offs, pbase);
        k_gather<<<GCAP_, 256, 0, stream>>>(x, list, counts, pbase, xh, xl);

        k_g5<0><<<(T_ / 128) * (F_ / 128) * E_, 256, 0, stream>>>(
            xh, xl, wph, wpl, b1, nullptr, hh, hl, list, counts, pbase, nullptr);
        k_convert_w<<<dim3(D_ / 128, F_ / 32, E_), 256, 0, stream>>>(w2, wph, wpl, F_, D_);
        k_g5<1><<<(T_ / 128) * (D_ / 128) * E_, 256, 0, stream>>>(
            hh, hl, wph, wpl, b2, out, nullptr, nullptr, list, counts, pbase, gate);
    } else if (ws_size >= need_B) {
        ushort_t* hh  = (ushort_t*)d_ws;
        ushort_t* hl  = hh + hf;
        ushort_t* xh  = hl + hf;
        ushort_t* xl  = xh + xd;
        ushort_t* wph = xl + xd;
        ushort_t* wpl = wph + WCAP;
        float* r    = (float*)(wpl + WCAP);
        float* gate = r + (size_t)T_ * E_;
        int* list   = (int*)(gate + T_);
        int* counts = list + (size_t)E_ * T_;
        int* offs   = counts + E_;
        int* pbase  = offs + E_;

        k_router<<<T_ / 4, 256, 0, stream>>>(x, rw, r, counts);
        k_convert_x<<<(int)(xd / 2048), 256, 0, stream>>>(x, xh, xl);
        k_convert_w<<<dim3(F_ / 128, D_ / 32, E_), 256, 0, stream>>>(w1, wph, wpl, D_, F_);
        k_scan<<<B_ * E_, 64, 0, stream>>>(r);
        k_route<<<T_ / 256, 256, 0, stream>>>(r, gate, list, counts);
        k_offs<<<1, 64, 0, stream>>>(counts, offs, pbase);

        k_gemm2<0><<<dim3(T_ / 128, F_ / 128, E_), 256, 0, stream>>>(
            xh, xl, wph, wpl, b1, nullptr, hh, hl, list, counts, offs, nullptr,
            D_, F_, F_ / 16);
        k_convert_w<<<dim3(D_ / 128, F_ / 32, E_), 256, 0, stream>>>(w2, wph, wpl, F_, D_);
        k_gemm2<1><<<dim3(T_ / 128, D_ / 128, E_), 256, 0, stream>>>(
            hh, hl, wph, wpl, b2, out, nullptr, nullptr, list, counts, offs, gate,
            F_, D_, D_ / 16);
    }
    // else: ws too small -> leave poison, fail loudly
}

// Round 6
// 989.823 us; speedup vs baseline: 1.0641x; 1.0641x over previous
//
#include <hip/hip_runtime.h>
#include <math.h>

#define B_ 4
#define S_ 2048
#define D_ 1024
#define F_ 4096
#define E_ 4
#define T_ (B_*S_)        // 8192 tokens
#define PCAP_ 8704        // max padded rows: 8192 + 4*127 rounded to 128
#define GCAP_ (PCAP_/16)  // 544 row-groups

typedef unsigned short ushort_t;
typedef __attribute__((ext_vector_type(8))) short short8;
typedef __attribute__((ext_vector_type(4))) float f32x4;

__device__ __forceinline__ ushort_t f2bf_rne(float f) {
    unsigned u = __float_as_uint(f);
    unsigned r = 0x7FFFu + ((u >> 16) & 1u);
    u += r;
    return (ushort_t)(u >> 16);
}
__device__ __forceinline__ float bf2f(ushort_t h) {
    return __uint_as_float(((unsigned)h) << 16);
}
__device__ __forceinline__ void split_bf16(float f, ushort_t &hi, ushort_t &lo) {
    hi = f2bf_rne(f);
    lo = f2bf_rne(f - bf2f(hi));
}

__device__ __forceinline__ void gload16(const void* g, void* l) {
    __builtin_amdgcn_global_load_lds(
        (const __attribute__((address_space(1))) unsigned int*)g,
        (__attribute__((address_space(3))) unsigned int*)l, 16, 0, 0);
}

// ---------------- routing ----------------

__global__ void k_router(const float* __restrict__ x, const float* __restrict__ rw,
                         float* __restrict__ r, int* __restrict__ counts) {
    if (blockIdx.x == 0 && threadIdx.x < E_) counts[threadIdx.x] = 0;
    int wid = blockIdx.x * 4 + (threadIdx.x >> 6);
    int lane = threadIdx.x & 63;
    const float* xr = x + (size_t)wid * D_;
    float a0 = 0.f, a1 = 0.f, a2 = 0.f, a3 = 0.f;
    for (int i = lane; i < D_; i += 64) {
        float xv = xr[i];
        float4 w = reinterpret_cast<const float4*>(rw)[i];
        a0 += xv * w.x; a1 += xv * w.y; a2 += xv * w.z; a3 += xv * w.w;
    }
    for (int off = 32; off; off >>= 1) {
        a0 += __shfl_down(a0, off, 64);
        a1 += __shfl_down(a1, off, 64);
        a2 += __shfl_down(a2, off, 64);
        a3 += __shfl_down(a3, off, 64);
    }
    if (lane == 0) {
        float4 v; v.x = a0; v.y = a1; v.z = a2; v.w = a3;
        reinterpret_cast<float4*>(r)[wid] = v;
    }
}

__global__ void k_scan(float* __restrict__ r) {
    int b = blockIdx.x >> 2, e = blockIdx.x & 3;
    int lane = threadIdx.x;
    float carry = 0.f;
    for (int c = 0; c < S_ / 64; ++c) {
        int s = c * 64 + lane;
        float* p = r + ((size_t)(b * S_ + s)) * E_ + e;
        float v = *p;
        #pragma unroll
        for (int off = 1; off < 64; off <<= 1) {
            float u = __shfl_up(v, off, 64);
            if (lane >= off) v += u;
        }
        v += carry;
        *p = v;
        carry = __shfl(v, 63, 64);
    }
}

__global__ void k_route(const float* __restrict__ r, float* __restrict__ gate,
                        int* __restrict__ list, int* __restrict__ counts) {
    int t = blockIdx.x * blockDim.x + threadIdx.x;
    if (t >= T_) return;
    int s = t & (S_ - 1);
    float4 l4 = reinterpret_cast<const float4*>(r)[t];
    float inv = 1.f / (float)(s + 1);
    float l[4] = { l4.x * inv, l4.y * inv, l4.z * inv, l4.w * inv };
    int best = 0; float m = l[0];
    #pragma unroll
    for (int e = 1; e < 4; ++e) if (l[e] > m) { m = l[e]; best = e; }
    float sum = 0.f;
    #pragma unroll
    for (int e = 0; e < 4; ++e) sum += expf(l[e] - m);
    gate[t] = 1.f / sum;
    int pos = atomicAdd(&counts[best], 1);
    list[best * T_ + pos] = t;
}

__global__ void k_offs(const int* __restrict__ counts, int* __restrict__ offs,
                       int* __restrict__ pbase) {
    if (threadIdx.x == 0) {
        int a = 0, p = 0;
        pbase[0] = 0;
        for (int e = 0; e < E_; ++e) {
            offs[e] = a; a += counts[e];
            p += (counts[e] + 127) & ~127;
            pbase[e + 1] = p;
        }
    }
}

// ---------------- gather x into padded expert order, frag-tiled hi/lo ----------------
__global__ __launch_bounds__(256)
void k_gather(const float* __restrict__ x, const int* __restrict__ list,
              const int* __restrict__ counts, const int* __restrict__ pbase,
              ushort_t* __restrict__ Xh, ushort_t* __restrict__ Xl)
{
    constexpr int KB = D_ / 32;
    const int g = blockIdx.x;
    const int r15 = threadIdx.x & 15;
    const int kq = threadIdx.x >> 4;
    const int v = g * 16 + r15;
    int e = 0;
    #pragma unroll
    for (int i = 0; i < E_; ++i) if (v >= pbase[i + 1]) e = i + 1;
    int token = -1;
    if (e < E_) {
        int local = v - pbase[e];
        if (local < counts[e]) token = list[e * T_ + local];
    }
    const float* xr = x + (size_t)(token >= 0 ? token : 0) * D_;
    #pragma unroll
    for (int c8 = 0; c8 < 8; ++c8) {
        const int k = kq * 64 + c8 * 8;
        float vv[8];
        if (token >= 0) {
            float4 u0 = *reinterpret_cast<const float4*>(xr + k);
            float4 u1 = *reinterpret_cast<const float4*>(xr + k + 4);
            vv[0]=u0.x; vv[1]=u0.y; vv[2]=u0.z; vv[3]=u0.w;
            vv[4]=u1.x; vv[5]=u1.y; vv[6]=u1.z; vv[7]=u1.w;
        } else {
            #pragma unroll
            for (int j = 0; j < 8; ++j) vv[j] = 0.f;
        }
        unsigned hw[4], lw[4];
        #pragma unroll
        for (int j = 0; j < 4; ++j) {
            ushort_t h0, l0, h1, l1;
            split_bf16(vv[2*j], h0, l0);
            split_bf16(vv[2*j+1], h1, l1);
            hw[j] = (unsigned)h0 | ((unsigned)h1 << 16);
            lw[j] = (unsigned)l0 | ((unsigned)l1 << 16);
        }
        size_t off = (((size_t)g * KB + (k >> 5)) * 64 + ((k >> 3) & 3) * 16 + r15) * 8;
        *reinterpret_cast<uint4*>(Xh + off) = make_uint4(hw[0], hw[1], hw[2], hw[3]);
        *reinterpret_cast<uint4*>(Xl + off) = make_uint4(lw[0], lw[1], lw[2], lw[3]);
    }
}

// ---------------- weight conversion to frag-order planes ----------------
__global__ __launch_bounds__(256)
void k_convert_w(const float* __restrict__ W, ushort_t* __restrict__ Ph,
                 ushort_t* __restrict__ Pl, int K, int N) {
    const int e = blockIdx.z;
    const int n0 = blockIdx.x * 128;
    const int k0 = blockIdx.y * 32;
    const int kb = blockIdx.y;
    const int NT = N >> 4, KB = K >> 5;
    __shared__ float lf[32 * 128];
    const float* We = W + (size_t)e * K * N;
    const int tid = threadIdx.x;
    #pragma unroll
    for (int i = 0; i < 4; ++i) {
        int q = i * 256 + tid;
        int k = q >> 5, c4 = q & 31;
        float4 v = *reinterpret_cast<const float4*>(We + (size_t)(k0 + k) * N + n0 + c4 * 4);
        *reinterpret_cast<float4*>(lf + k * 128 + c4 * 4) = v;
    }
    __syncthreads();
    #pragma unroll
    for (int p = 0; p < 2; ++p) {
        int q = p * 256 + tid;
        int n = q & 127, kg = q >> 7;
        unsigned hw[4], lw[4];
        #pragma unroll
        for (int j = 0; j < 8; j += 2) {
            float f0 = lf[(kg * 8 + j) * 128 + n];
            float f1 = lf[(kg * 8 + j + 1) * 128 + n];
            ushort_t h0, l0, h1, l1;
            split_bf16(f0, h0, l0);
            split_bf16(f1, h1, l1);
            hw[j >> 1] = (unsigned)h0 | ((unsigned)h1 << 16);
            lw[j >> 1] = (unsigned)l0 | ((unsigned)l1 << 16);
        }
        size_t off = ((((size_t)e * NT + ((n0 + n) >> 4)) * KB + kb) * 64
                      + (kg * 16 + (n & 15))) * 8;
        *reinterpret_cast<uint4*>(Ph + off) = make_uint4(hw[0], hw[1], hw[2], hw[3]);
        *reinterpret_cast<uint4*>(Pl + off) = make_uint4(lw[0], lw[1], lw[2], lw[3]);
    }
}

// ---------------- main grouped GEMMs: flatmm (A in regs, B-only LDS) ----------------
// MODE 0: h(frag-order planes) = gelu(Xg @ w1 + b1)   K=1024, N=4096
// MODE 1: out(scatter,f32)     = gate*(h @ w2 + b2)   K=4096, N=1024
// Block 512 thr = 8 waves, tile 128x128; wave tile 32(M) x 128(N), BK=32.
// A hi/lo: global->VGPR (double reg set). B hi/lo: gload16 to LDS, dbuf 32KB.
// Per step: issue B(t+1)[2] + A(t+1)[4] -> ds_read 8 B-frags -> lgkm(0) ->
// vmcnt(6) -> 24 MFMA -> vmcnt(4) -> s_barrier. vmcnt never 0 in steady state.
template<int MODE>
__global__ __launch_bounds__(512, 4)
void k_g6(const ushort_t* __restrict__ Ah, const ushort_t* __restrict__ Al,
          const ushort_t* __restrict__ Bh, const ushort_t* __restrict__ Bl,
          const float* __restrict__ bias, float* __restrict__ outF,
          ushort_t* __restrict__ outHh, ushort_t* __restrict__ outHl,
          const int* __restrict__ list, const int* __restrict__ counts,
          const int* __restrict__ pbase, const float* __restrict__ gate)
{
    constexpr int K  = (MODE == 0) ? D_ : F_;
    constexpr int N  = (MODE == 0) ? F_ : D_;
    constexpr int KB = K / 32;
    constexpr int NT = N / 16;
    constexpr int KBH = F_ / 32;

    const int e = blockIdx.z;
    const int cnt = counts[e];
    const int m0 = blockIdx.x * 128;
    if (m0 >= cnt) return;
    const int n0 = blockIdx.y * 128;
    const int pb = pbase[e];
    const int tid = threadIdx.x, wid = tid >> 6, lane = tid & 63;
    const int l15 = lane & 15, lkg = lane >> 4;
    const int wrow = wid >> 1, wcol = wid & 1;   // 4 row-quarters x 2 col-halves
    const int G0 = (pb + m0) >> 4;

    // LDS: 2 buffers x (Bh 8nt x 512 @0, Bl @4096) shorts = 16KB each
    __shared__ __align__(16) ushort_t lds[2][8192];

    // A sources (frag-order planes), per m-frag
    const ushort_t* apH[2]; const ushort_t* apL[2];
    #pragma unroll
    for (int mi = 0; mi < 2; ++mi) {
        size_t ab = ((size_t)(G0 + wrow * 2 + mi) * KB) * 512 + (size_t)lane * 8;
        apH[mi] = Ah + ab; apL[mi] = Al + ab;
    }
    // B staging source: wave wid stages nt-chunk wid (1KB per plane per step)
    const size_t bb = (((size_t)e * NT + (n0 >> 4) + wid) * KB) * 512 + (size_t)lane * 8;
    const ushort_t* bpH = Bh + bb;
    const ushort_t* bpL = Bl + bb;

    f32x4 acc[2][4];
    #pragma unroll
    for (int i = 0; i < 2; ++i)
        #pragma unroll
        for (int j = 0; j < 4; ++j) acc[i][j] = (f32x4){0.f, 0.f, 0.f, 0.f};

    short8 a0h[2], a0l[2], a1h[2], a1l[2];

    // ---- prologue: issue B(0) then A(0)->a0; wait B landed (A flying) ----
    gload16(bpH, &lds[0][wid * 512]);
    gload16(bpL, &lds[0][4096 + wid * 512]);
    __builtin_amdgcn_sched_barrier(0);
    a0h[0] = *reinterpret_cast<const short8*>(apH[0]);
    a0h[1] = *reinterpret_cast<const short8*>(apH[1]);
    a0l[0] = *reinterpret_cast<const short8*>(apL[0]);
    a0l[1] = *reinterpret_cast<const short8*>(apL[1]);
    __builtin_amdgcn_sched_barrier(0);
    asm volatile("s_waitcnt vmcnt(4)" ::: "memory");
    __builtin_amdgcn_sched_barrier(0);
    __builtin_amdgcn_s_barrier();

    #define STEP_(T, CH, CL, NH, NL)                                               \
    {                                                                              \
        const int nx = (T) + 1;                                                    \
        const ushort_t* bufc = &lds[(T) & 1][0];                                   \
        ushort_t* bufn = &lds[((T) + 1) & 1][0];                                   \
        if (nx < KB) {                                                             \
            gload16(bpH + (size_t)nx * 512, bufn + wid * 512);                     \
            gload16(bpL + (size_t)nx * 512, bufn + 4096 + wid * 512);              \
            __builtin_amdgcn_sched_barrier(0);                                     \
            NH[0] = *reinterpret_cast<const short8*>(apH[0] + (size_t)nx * 512);   \
            NH[1] = *reinterpret_cast<const short8*>(apH[1] + (size_t)nx * 512);   \
            NL[0] = *reinterpret_cast<const short8*>(apL[0] + (size_t)nx * 512);   \
            NL[1] = *reinterpret_cast<const short8*>(apL[1] + (size_t)nx * 512);   \
        }                                                                          \
        __builtin_amdgcn_sched_barrier(0);                                         \
        short8 bhv[4], blv[4];                                                     \
        _Pragma("unroll")                                                          \
        for (int ni = 0; ni < 4; ++ni) {                                           \
            const int nt = wcol * 4 + ni;                                          \
            bhv[ni] = *reinterpret_cast<const short8*>(&bufc[nt * 512 + lane * 8]);\
            blv[ni] = *reinterpret_cast<const short8*>(&bufc[4096 + nt * 512 + lane * 8]); \
        }                                                                          \
        asm volatile("s_waitcnt lgkmcnt(0)" ::: "memory");                         \
        if (nx < KB) { asm volatile("s_waitcnt vmcnt(6)" ::: "memory"); }          \
        else         { asm volatile("s_waitcnt vmcnt(0)" ::: "memory"); }          \
        __builtin_amdgcn_sched_barrier(0);                                         \
        __builtin_amdgcn_s_setprio(1);                                             \
        _Pragma("unroll")                                                          \
        for (int mi = 0; mi < 2; ++mi)                                             \
            _Pragma("unroll")                                                      \
            for (int ni = 0; ni < 4; ++ni) {                                       \
                acc[mi][ni] = __builtin_amdgcn_mfma_f32_16x16x32_bf16(CH[mi], bhv[ni], acc[mi][ni], 0, 0, 0); \
                acc[mi][ni] = __builtin_amdgcn_mfma_f32_16x16x32_bf16(CH[mi], blv[ni], acc[mi][ni], 0, 0, 0); \
                acc[mi][ni] = __builtin_amdgcn_mfma_f32_16x16x32_bf16(CL[mi], bhv[ni], acc[mi][ni], 0, 0, 0); \
            }                                                                      \
        __builtin_amdgcn_s_setprio(0);                                             \
        __builtin_amdgcn_sched_barrier(0);                                         \
        if (nx < KB) { asm volatile("s_waitcnt vmcnt(4)" ::: "memory"); }          \
        else         { asm volatile("s_waitcnt vmcnt(0)" ::: "memory"); }          \
        __builtin_amdgcn_sched_barrier(0);                                         \
        __builtin_amdgcn_s_barrier();                                              \
    }

    for (int t = 0; t < KB; t += 2) {
        STEP_(t, a0h, a0l, a1h, a1l);
        STEP_(t + 1, a1h, a1l, a0h, a0l);
    }
    #undef STEP_

    const float* be = bias + (size_t)e * N;
    if (MODE == 0) {
        #pragma unroll
        for (int mi = 0; mi < 2; ++mi) {
            const int g2 = G0 + wrow * 2 + mi;
            #pragma unroll
            for (int rg = 0; rg < 4; ++rg) {
                const int r15o = lkg * 4 + rg;
                #pragma unroll
                for (int ni = 0; ni < 4; ++ni) {
                    const int f = n0 + wcol * 64 + ni * 16 + l15;
                    float v = acc[mi][ni][rg] + be[f];
                    float u = 1.5957691216057308f * (v + 0.044715f * v * v * v);
                    v = v / (1.f + __expf(-u));
                    ushort_t h, l;
                    split_bf16(v, h, l);
                    size_t off = (((size_t)g2 * KBH + (f >> 5)) * 64
                                  + ((f >> 3) & 3) * 16 + r15o) * 8 + (f & 7);
                    outHh[off] = h;
                    outHl[off] = l;
                }
            }
        }
    } else {
        const int* lst = list + (size_t)e * T_;
        #pragma unroll
        for (int mi = 0; mi < 2; ++mi) {
            #pragma unroll
            for (int rg = 0; rg < 4; ++rg) {
                int rm = m0 + wrow * 32 + mi * 16 + lkg * 4 + rg;
                if (rm >= cnt) continue;
                int t = lst[rm];
                float gv = gate[t];
                float* crow = outF + (size_t)t * (size_t)N;
                #pragma unroll
                for (int ni = 0; ni < 4; ++ni) {
                    int col = n0 + wcol * 64 + ni * 16 + l15;
                    crow[col] = gv * (acc[mi][ni][rg] + be[col]);
                }
            }
        }
    }
}

// ---------------- tier-B fallback (round-2 proven path) ----------------

__global__ void k_convert_x(const float* __restrict__ x,
                            ushort_t* __restrict__ xh, ushort_t* __restrict__ xl) {
    size_t i = ((size_t)blockIdx.x * 256 + threadIdx.x) * 8;
    float4 a = *reinterpret_cast<const float4*>(x + i);
    float4 b = *reinterpret_cast<const float4*>(x + i + 4);
    float v[8] = { a.x, a.y, a.z, a.w, b.x, b.y, b.z, b.w };
    unsigned hw[4], lw[4];
    #pragma unroll
    for (int j = 0; j < 4; ++j) {
        ushort_t h0, l0, h1, l1;
        split_bf16(v[2*j], h0, l0);
        split_bf16(v[2*j+1], h1, l1);
        hw[j] = (unsigned)h0 | ((unsigned)h1 << 16);
        lw[j] = (unsigned)l0 | ((unsigned)l1 << 16);
    }
    *reinterpret_cast<uint4*>(xh + i) = make_uint4(hw[0], hw[1], hw[2], hw[3]);
    *reinterpret_cast<uint4*>(xl + i) = make_uint4(lw[0], lw[1], lw[2], lw[3]);
}

template<int MODE>
__global__ __launch_bounds__(256)
void k_gemm2(const ushort_t* __restrict__ Ah, const ushort_t* __restrict__ Al,
             const ushort_t* __restrict__ Bh, const ushort_t* __restrict__ Bl,
             const float* __restrict__ bias, float* __restrict__ outF,
             ushort_t* __restrict__ outHh, ushort_t* __restrict__ outHl,
             const int* __restrict__ list, const int* __restrict__ counts,
             const int* __restrict__ offs, const float* __restrict__ gate,
             int K, int N, int NT)
{
    const int e = blockIdx.z;
    const int cnt = counts[e];
    const int m0 = blockIdx.x * 128;
    if (m0 >= cnt) return;
    const int n0 = blockIdx.y * 128;
    const int hbase = offs[e];
    const int KB = K >> 5;
    const int tid = threadIdx.x, wid = tid >> 6, lane = tid & 63;
    const int l15 = lane & 15, lkg = lane >> 4;
    const int* lst = list + (size_t)e * T_;
    __shared__ __align__(16) ushort_t lds[16384];
    size_t a_rel[2], b_rel[2];
    #pragma unroll
    for (int i = 0; i < 2; ++i) {
        int rf = wid * 2 + i;
        int rm = m0 + rf * 16 + l15;
        int rr = rm < cnt ? rm : cnt - 1;
        size_t row = (MODE == 0) ? (size_t)lst[rr] : (size_t)(hbase + rr);
        a_rel[i] = row * (size_t)K + (size_t)lkg * 8;
        b_rel[i] = (((size_t)e * NT + (n0 >> 4) + rf) * (size_t)KB) * 512 + (size_t)lane * 8;
    }
    const int wr = wid >> 1, wc = wid & 1;
    f32x4 acc[4][4];
    #pragma unroll
    for (int i = 0; i < 4; ++i)
        #pragma unroll
        for (int j = 0; j < 4; ++j) acc[i][j] = (f32x4){0.f, 0.f, 0.f, 0.f};
    for (int kb = 0; kb < KB; ++kb) {
        __syncthreads();
        #pragma unroll
        for (int i = 0; i < 2; ++i) {
            int c = wid * 2 + i;
            gload16(Ah + a_rel[i] + (size_t)kb * 32, &lds[c * 512]);
            gload16(Al + a_rel[i] + (size_t)kb * 32, &lds[4096 + c * 512]);
            gload16(Bh + b_rel[i] + (size_t)kb * 512, &lds[8192 + c * 512]);
            gload16(Bl + b_rel[i] + (size_t)kb * 512, &lds[12288 + c * 512]);
        }
        __syncthreads();
        short8 ah[4], al[4], bh[4], bl[4];
        #pragma unroll
        for (int mi = 0; mi < 4; ++mi) {
            int rf = wr * 4 + mi;
            ah[mi] = *reinterpret_cast<const short8*>(&lds[rf * 512 + lane * 8]);
            al[mi] = *reinterpret_cast<const short8*>(&lds[4096 + rf * 512 + lane * 8]);
        }
        #pragma unroll
        for (int ni = 0; ni < 4; ++ni) {
            int nt = wc * 4 + ni;
            bh[ni] = *reinterpret_cast<const short8*>(&lds[8192 + nt * 512 + lane * 8]);
            bl[ni] = *reinterpret_cast<const short8*>(&lds[12288 + nt * 512 + lane * 8]);
        }
        #pragma unroll
        for (int mi = 0; mi < 4; ++mi)
            #pragma unroll
            for (int ni = 0; ni < 4; ++ni) {
                acc[mi][ni] = __builtin_amdgcn_mfma_f32_16x16x32_bf16(ah[mi], bh[ni], acc[mi][ni], 0, 0, 0);
                acc[mi][ni] = __builtin_amdgcn_mfma_f32_16x16x32_bf16(ah[mi], bl[ni], acc[mi][ni], 0, 0, 0);
                acc[mi][ni] = __builtin_amdgcn_mfma_f32_16x16x32_bf16(al[mi], bh[ni], acc[mi][ni], 0, 0, 0);
            }
    }
    const float* be = bias + (size_t)e * N;
    #pragma unroll
    for (int mi = 0; mi < 4; ++mi) {
        #pragma unroll
        for (int rg = 0; rg < 4; ++rg) {
            int rm = m0 + wr * 64 + mi * 16 + lkg * 4 + rg;
            if (rm >= cnt) continue;
            if (MODE == 0) {
                size_t rowb = (size_t)(hbase + rm) * (size_t)F_;
                #pragma unroll
                for (int ni = 0; ni < 4; ++ni) {
                    int col = n0 + wc * 64 + ni * 16 + l15;
                    float v = acc[mi][ni][rg] + be[col];
                    float u = 1.5957691216057308f * (v + 0.044715f * v * v * v);
                    v = v / (1.f + __expf(-u));
                    ushort_t h, l;
                    split_bf16(v, h, l);
                    outHh[rowb + col] = h;
                    outHl[rowb + col] = l;
                }
            } else {
                int t = lst[rm];
                float gv = gate[t];
                float* crow = outF + (size_t)t * (size_t)N;
                #pragma unroll
                for (int ni = 0; ni < 4; ++ni) {
                    int col = n0 + wc * 64 + ni * 16 + l15;
                    crow[col] = gv * (acc[mi][ni][rg] + be[col]);
                }
            }
        }
    }
}

// ---------------- launch ----------------

extern "C" void kernel_launch(void* const* d_in, const int* in_sizes, int n_in,
                              void* d_out, int out_size, void* d_ws, size_t ws_size,
                              hipStream_t stream) {
    const float* x   = (const float*)d_in[0];
    const float* rw  = (const float*)d_in[1];
    const float* w1  = (const float*)d_in[2];
    const float* b1  = (const float*)d_in[3];
    const float* w2  = (const float*)d_in[4];
    const float* b2  = (const float*)d_in[5];
    float* out = (float*)d_out;

    const size_t HCAP = (size_t)PCAP_ * F_;
    const size_t XCAP = (size_t)PCAP_ * D_;
    const size_t WCAP = (size_t)E_ * D_ * F_;
    const size_t misc = ((size_t)T_ * E_ + T_ + (size_t)E_ * T_) * 4 + 256;

    const size_t need_A = (2 * HCAP + 2 * XCAP + 2 * WCAP) * 2 + misc;   // ~246 MB
    const size_t hf = (size_t)T_ * F_;
    const size_t xd = (size_t)T_ * D_;
    const size_t need_B = (2 * hf + 2 * xd + 2 * WCAP) * 2 + misc;       // ~201 MB

    if (ws_size >= need_A) {
        ushort_t* hh  = (ushort_t*)d_ws;
        ushort_t* hl  = hh + HCAP;
        ushort_t* xh  = hl + HCAP;
        ushort_t* xl  = xh + XCAP;
        ushort_t* wph = xl + XCAP;
        ushort_t* wpl = wph + WCAP;
        float* r    = (float*)(wpl + WCAP);
        float* gate = r + (size_t)T_ * E_;
        int* list   = (int*)(gate + T_);
        int* counts = list + (size_t)E_ * T_;
        int* offs   = counts + E_;
        int* pbase  = offs + E_;

        k_router<<<T_ / 4, 256, 0, stream>>>(x, rw, r, counts);
        k_convert_w<<<dim3(F_ / 128, D_ / 32, E_), 256, 0, stream>>>(w1, wph, wpl, D_, F_);
        k_scan<<<B_ * E_, 64, 0, stream>>>(r);
        k_route<<<T_ / 256, 256, 0, stream>>>(r, gate, list, counts);
        k_offs<<<1, 64, 0, stream>>>(counts, offs, pbase);
        k_gather<<<GCAP_, 256, 0, stream>>>(x, list, counts, pbase, xh, xl);

        k_g6<0><<<dim3(T_ / 128, F_ / 128, E_), 512, 0, stream>>>(
            xh, xl, wph, wpl, b1, nullptr, hh, hl, list, counts, pbase, nullptr);
        k_convert_w<<<dim3(D_ / 128, F_ / 32, E_), 256, 0, stream>>>(w2, wph, wpl, F_, D_);
        k_g6<1><<<dim3(T_ / 128, D_ / 128, E_), 512, 0, stream>>>(
            hh, hl, wph, wpl, b2, out, nullptr, nullptr, list, counts, pbase, gate);
    } else if (ws_size >= need_B) {
        ushort_t* hh  = (ushort_t*)d_ws;
        ushort_t* hl  = hh + hf;
        ushort_t* xh  = hl + hf;
        ushort_t* xl  = xh + xd;
        ushort_t* wph = xl + xd;
        ushort_t* wpl = wph + WCAP;
        float* r    = (float*)(wpl + WCAP);
        float* gate = r + (size_t)T_ * E_;
        int* list   = (int*)(gate + T_);
        int* counts = list + (size_t)E_ * T_;
        int* offs   = counts + E_;
        int* pbase  = offs + E_;

        k_router<<<T_ / 4, 256, 0, stream>>>(x, rw, r, counts);
        k_convert_x<<<(int)(xd / 2048), 256, 0, stream>>>(x, xh, xl);
        k_convert_w<<<dim3(F_ / 128, D_ / 32, E_), 256, 0, stream>>>(w1, wph, wpl, D_, F_);
        k_scan<<<B_ * E_, 64, 0, stream>>>(r);
        k_route<<<T_ / 256, 256, 0, stream>>>(r, gate, list, counts);
        k_offs<<<1, 64, 0, stream>>>(counts, offs, pbase);

        k_gemm2<0><<<dim3(T_ / 128, F_ / 128, E_), 256, 0, stream>>>(
            xh, xl, wph, wpl, b1, nullptr, hh, hl, list, counts, offs, nullptr,
            D_, F_, F_ / 16);
        k_convert_w<<<dim3(D_ / 128, F_ / 32, E_), 256, 0, stream>>>(w2, wph, wpl, F_, D_);
        k_gemm2<1><<<dim3(T_ / 128, D_ / 128, E_), 256, 0, stream>>>(
            hh, hl, wph, wpl, b2, out, nullptr, nullptr, list, counts, offs, gate,
            F_, D_, D_ / 16);
    }
    // else: ws too small -> leave poison, fail loudly
}

// Round 8
// 942.057 us; speedup vs baseline: 1.1180x; 1.0507x over previous
//
#include <hip/hip_runtime.h>
#include <math.h>

#define B_ 4
#define S_ 2048
#define D_ 1024
#define F_ 4096
#define E_ 4
#define T_ (B_*S_)        // 8192 tokens
#define PCAP_ 8704        // max padded rows: 8192 + 4*127 rounded to 128
#define GCAP_ (PCAP_/16)  // 544 row-groups

typedef unsigned short ushort_t;
typedef __attribute__((ext_vector_type(8))) short short8;
typedef __attribute__((ext_vector_type(4))) float f32x4;

__device__ __forceinline__ ushort_t f2bf_rne(float f) {
    unsigned u = __float_as_uint(f);
    unsigned r = 0x7FFFu + ((u >> 16) & 1u);
    u += r;
    return (ushort_t)(u >> 16);
}
__device__ __forceinline__ float bf2f(ushort_t h) {
    return __uint_as_float(((unsigned)h) << 16);
}
__device__ __forceinline__ void split_bf16(float f, ushort_t &hi, ushort_t &lo) {
    hi = f2bf_rne(f);
    lo = f2bf_rne(f - bf2f(hi));
}

__device__ __forceinline__ void gload16(const void* g, void* l) {
    __builtin_amdgcn_global_load_lds(
        (const __attribute__((address_space(1))) unsigned int*)g,
        (__attribute__((address_space(3))) unsigned int*)l, 16, 0, 0);
}

// ---------------- routing ----------------

__global__ void k_router(const float* __restrict__ x, const float* __restrict__ rw,
                         float* __restrict__ r, int* __restrict__ counts) {
    if (blockIdx.x == 0 && threadIdx.x < E_) counts[threadIdx.x] = 0;
    int wid = blockIdx.x * 4 + (threadIdx.x >> 6);
    int lane = threadIdx.x & 63;
    const float* xr = x + (size_t)wid * D_;
    float a0 = 0.f, a1 = 0.f, a2 = 0.f, a3 = 0.f;
    for (int i = lane; i < D_; i += 64) {
        float xv = xr[i];
        float4 w = reinterpret_cast<const float4*>(rw)[i];
        a0 += xv * w.x; a1 += xv * w.y; a2 += xv * w.z; a3 += xv * w.w;
    }
    for (int off = 32; off; off >>= 1) {
        a0 += __shfl_down(a0, off, 64);
        a1 += __shfl_down(a1, off, 64);
        a2 += __shfl_down(a2, off, 64);
        a3 += __shfl_down(a3, off, 64);
    }
    if (lane == 0) {
        float4 v; v.x = a0; v.y = a1; v.z = a2; v.w = a3;
        reinterpret_cast<float4*>(r)[wid] = v;
    }
}

__global__ void k_scan(float* __restrict__ r) {
    int b = blockIdx.x >> 2, e = blockIdx.x & 3;
    int lane = threadIdx.x;
    float carry = 0.f;
    for (int c = 0; c < S_ / 64; ++c) {
        int s = c * 64 + lane;
        float* p = r + ((size_t)(b * S_ + s)) * E_ + e;
        float v = *p;
        #pragma unroll
        for (int off = 1; off < 64; off <<= 1) {
            float u = __shfl_up(v, off, 64);
            if (lane >= off) v += u;
        }
        v += carry;
        *p = v;
        carry = __shfl(v, 63, 64);
    }
}

__global__ void k_route(const float* __restrict__ r, float* __restrict__ gate,
                        int* __restrict__ list, int* __restrict__ counts) {
    int t = blockIdx.x * blockDim.x + threadIdx.x;
    if (t >= T_) return;
    int s = t & (S_ - 1);
    float4 l4 = reinterpret_cast<const float4*>(r)[t];
    float inv = 1.f / (float)(s + 1);
    float l[4] = { l4.x * inv, l4.y * inv, l4.z * inv, l4.w * inv };
    int best = 0; float m = l[0];
    #pragma unroll
    for (int e = 1; e < 4; ++e) if (l[e] > m) { m = l[e]; best = e; }
    float sum = 0.f;
    #pragma unroll
    for (int e = 0; e < 4; ++e) sum += expf(l[e] - m);
    gate[t] = 1.f / sum;
    int pos = atomicAdd(&counts[best], 1);
    list[best * T_ + pos] = t;
}

__global__ void k_offs(const int* __restrict__ counts, int* __restrict__ offs,
                       int* __restrict__ pbase) {
    if (threadIdx.x == 0) {
        int a = 0, p = 0;
        pbase[0] = 0;
        for (int e = 0; e < E_; ++e) {
            offs[e] = a; a += counts[e];
            p += (counts[e] + 127) & ~127;
            pbase[e + 1] = p;
        }
    }
}

// ---------------- gather x into padded expert order, frag-tiled hi/lo ----------------
__global__ __launch_bounds__(256)
void k_gather(const float* __restrict__ x, const int* __restrict__ list,
              const int* __restrict__ counts, const int* __restrict__ pbase,
              ushort_t* __restrict__ Xh, ushort_t* __restrict__ Xl)
{
    constexpr int KB = D_ / 32;
    const int g = blockIdx.x;
    const int r15 = threadIdx.x & 15;
    const int kq = threadIdx.x >> 4;
    const int v = g * 16 + r15;
    int e = 0;
    #pragma unroll
    for (int i = 0; i < E_; ++i) if (v >= pbase[i + 1]) e = i + 1;
    int token = -1;
    if (e < E_) {
        int local = v - pbase[e];
        if (local < counts[e]) token = list[e * T_ + local];
    }
    const float* xr = x + (size_t)(token >= 0 ? token : 0) * D_;
    #pragma unroll
    for (int c8 = 0; c8 < 8; ++c8) {
        const int k = kq * 64 + c8 * 8;
        float vv[8];
        if (token >= 0) {
            float4 u0 = *reinterpret_cast<const float4*>(xr + k);
            float4 u1 = *reinterpret_cast<const float4*>(xr + k + 4);
            vv[0]=u0.x; vv[1]=u0.y; vv[2]=u0.z; vv[3]=u0.w;
            vv[4]=u1.x; vv[5]=u1.y; vv[6]=u1.z; vv[7]=u1.w;
        } else {
            #pragma unroll
            for (int j = 0; j < 8; ++j) vv[j] = 0.f;
        }
        unsigned hw[4], lw[4];
        #pragma unroll
        for (int j = 0; j < 4; ++j) {
            ushort_t h0, l0, h1, l1;
            split_bf16(vv[2*j], h0, l0);
            split_bf16(vv[2*j+1], h1, l1);
            hw[j] = (unsigned)h0 | ((unsigned)h1 << 16);
            lw[j] = (unsigned)l0 | ((unsigned)l1 << 16);
        }
        size_t off = (((size_t)g * KB + (k >> 5)) * 64 + ((k >> 3) & 3) * 16 + r15) * 8;
        *reinterpret_cast<uint4*>(Xh + off) = make_uint4(hw[0], hw[1], hw[2], hw[3]);
        *reinterpret_cast<uint4*>(Xl + off) = make_uint4(lw[0], lw[1], lw[2], lw[3]);
    }
}

// ---------------- weight conversion to frag-order planes ----------------
__global__ __launch_bounds__(256)
void k_convert_w(const float* __restrict__ W, ushort_t* __restrict__ Ph,
                 ushort_t* __restrict__ Pl, int K, int N) {
    const int e = blockIdx.z;
    const int n0 = blockIdx.x * 128;
    const int k0 = blockIdx.y * 32;
    const int kb = blockIdx.y;
    const int NT = N >> 4, KB = K >> 5;
    __shared__ float lf[32 * 128];
    const float* We = W + (size_t)e * K * N;
    const int tid = threadIdx.x;
    #pragma unroll
    for (int i = 0; i < 4; ++i) {
        int q = i * 256 + tid;
        int k = q >> 5, c4 = q & 31;
        float4 v = *reinterpret_cast<const float4*>(We + (size_t)(k0 + k) * N + n0 + c4 * 4);
        *reinterpret_cast<float4*>(lf + k * 128 + c4 * 4) = v;
    }
    __syncthreads();
    #pragma unroll
    for (int p = 0; p < 2; ++p) {
        int q = p * 256 + tid;
        int n = q & 127, kg = q >> 7;
        unsigned hw[4], lw[4];
        #pragma unroll
        for (int j = 0; j < 8; j += 2) {
            float f0 = lf[(kg * 8 + j) * 128 + n];
            float f1 = lf[(kg * 8 + j + 1) * 128 + n];
            ushort_t h0, l0, h1, l1;
            split_bf16(f0, h0, l0);
            split_bf16(f1, h1, l1);
            hw[j >> 1] = (unsigned)h0 | ((unsigned)h1 << 16);
            lw[j >> 1] = (unsigned)l0 | ((unsigned)l1 << 16);
        }
        size_t off = ((((size_t)e * NT + ((n0 + n) >> 4)) * KB + kb) * 64
                      + (kg * 16 + (n & 15))) * 8;
        *reinterpret_cast<uint4*>(Ph + off) = make_uint4(hw[0], hw[1], hw[2], hw[3]);
        *reinterpret_cast<uint4*>(Pl + off) = make_uint4(lw[0], lw[1], lw[2], lw[3]);
    }
}

// ---------------- main grouped GEMMs: depth-3 flatmm, RACE-FIXED ----------------
// Per-wave VMEM queue (issue order B then A, 6 ops/tile):
//   step t: [issue B(t+2),A(t+2) -> 16 out] vmcnt(12)=drain A(t) -> MFMA(tile t)
//           -> lgkm(0) -> vmcnt(10)=drain B(t+1) -> s_barrier  (cross-wave cert)
// Prologue: stage t0,t1 -> vmcnt(10)=drain B(0) -> barrier.
// Tails: vmcnt(6)/vmcnt(4), then vmcnt(0). Buffer rewrite always behind a
// barrier that followed lgkm(0) of its last reader. (k_g6 discipline, depth 3.)
template<int MODE>
__global__ __launch_bounds__(512, 4)
void k_g8(const ushort_t* __restrict__ Ah, const ushort_t* __restrict__ Al,
          const ushort_t* __restrict__ Bh, const ushort_t* __restrict__ Bl,
          const float* __restrict__ bias, float* __restrict__ outF,
          ushort_t* __restrict__ outHh, ushort_t* __restrict__ outHl,
          const int* __restrict__ list, const int* __restrict__ counts,
          const int* __restrict__ pbase, const float* __restrict__ gate)
{
    constexpr int K  = (MODE == 0) ? D_ : F_;
    constexpr int N  = (MODE == 0) ? F_ : D_;
    constexpr int KB = K / 32;            // 32 or 128, both == 2 (mod 3)
    constexpr int NT = N / 16;
    constexpr int KBH = F_ / 32;

    const int e = blockIdx.z;
    const int cnt = counts[e];
    const int m0 = blockIdx.x * 128;
    if (m0 >= cnt) return;
    const int n0 = blockIdx.y * 128;
    const int pb = pbase[e];
    const int tid = threadIdx.x, wid = tid >> 6, lane = tid & 63;
    const int l15 = lane & 15, lkg = lane >> 4;
    const int wrow = wid >> 1, wcol = wid & 1;
    const int G0 = (pb + m0) >> 4;

    // 3 B buffers: each = Bh[8nt][512] @0, Bl @4096 (ushort idx), 16KB each
    __shared__ __align__(16) ushort_t lds[3][8192];

    const ushort_t* apH[2]; const ushort_t* apL[2];
    #pragma unroll
    for (int mi = 0; mi < 2; ++mi) {
        size_t ab = ((size_t)(G0 + wrow * 2 + mi) * KB) * 512 + (size_t)lane * 8;
        apH[mi] = Ah + ab; apL[mi] = Al + ab;
    }
    const size_t bb = (((size_t)e * NT + (n0 >> 4) + wid) * KB) * 512 + (size_t)lane * 8;
    const ushort_t* bpH = Bh + bb;
    const ushort_t* bpL = Bl + bb;

    f32x4 acc[2][4];
    #pragma unroll
    for (int i = 0; i < 2; ++i)
        #pragma unroll
        for (int j = 0; j < 4; ++j) acc[i][j] = (f32x4){0.f, 0.f, 0.f, 0.f};

    // 3 rotating A register sets (all statically indexed)
    short8 aH0[2], aL0[2], aH1[2], aL1[2], aH2[2], aL2[2];

    // ---- prologue: issue {B0,A0}, {B1,A1}; certify B0 across waves ----
    gload16(bpH, &lds[0][wid * 512]);
    gload16(bpL, &lds[0][4096 + wid * 512]);
    aH0[0] = *reinterpret_cast<const short8*>(apH[0]);
    aH0[1] = *reinterpret_cast<const short8*>(apH[1]);
    aL0[0] = *reinterpret_cast<const short8*>(apL[0]);
    aL0[1] = *reinterpret_cast<const short8*>(apL[1]);
    __builtin_amdgcn_sched_barrier(0);
    gload16(bpH + 512, &lds[1][wid * 512]);
    gload16(bpL + 512, &lds[1][4096 + wid * 512]);
    aH1[0] = *reinterpret_cast<const short8*>(apH[0] + 512);
    aH1[1] = *reinterpret_cast<const short8*>(apH[1] + 512);
    aL1[0] = *reinterpret_cast<const short8*>(apL[0] + 512);
    aL1[1] = *reinterpret_cast<const short8*>(apL[1] + 512);
    __builtin_amdgcn_sched_barrier(0);
    asm volatile("s_waitcnt vmcnt(10)" ::: "memory");   // B0 landed (own)
    __builtin_amdgcn_sched_barrier(0);
    __builtin_amdgcn_s_barrier();                       // B0 visible to all

    #define COMPUTE_(SLOT, UH, UL)                                                  \
    {                                                                               \
        const ushort_t* bufc = &lds[(SLOT)][0];                                     \
        __builtin_amdgcn_s_setprio(1);                                              \
        short8 bh0 = *reinterpret_cast<const short8*>(&bufc[(wcol*4+0)*512 + lane*8]); \
        short8 bl0 = *reinterpret_cast<const short8*>(&bufc[4096 + (wcol*4+0)*512 + lane*8]); \
        short8 bh1 = *reinterpret_cast<const short8*>(&bufc[(wcol*4+1)*512 + lane*8]); \
        short8 bl1 = *reinterpret_cast<const short8*>(&bufc[4096 + (wcol*4+1)*512 + lane*8]); \
        _Pragma("unroll")                                                           \
        for (int mi = 0; mi < 2; ++mi) {                                            \
            acc[mi][0] = __builtin_amdgcn_mfma_f32_16x16x32_bf16(UH[mi], bh0, acc[mi][0], 0, 0, 0); \
            acc[mi][0] = __builtin_amdgcn_mfma_f32_16x16x32_bf16(UH[mi], bl0, acc[mi][0], 0, 0, 0); \
            acc[mi][0] = __builtin_amdgcn_mfma_f32_16x16x32_bf16(UL[mi], bh0, acc[mi][0], 0, 0, 0); \
            acc[mi][1] = __builtin_amdgcn_mfma_f32_16x16x32_bf16(UH[mi], bh1, acc[mi][1], 0, 0, 0); \
            acc[mi][1] = __builtin_amdgcn_mfma_f32_16x16x32_bf16(UH[mi], bl1, acc[mi][1], 0, 0, 0); \
            acc[mi][1] = __builtin_amdgcn_mfma_f32_16x16x32_bf16(UL[mi], bh1, acc[mi][1], 0, 0, 0); \
        }                                                                           \
        short8 bh2 = *reinterpret_cast<const short8*>(&bufc[(wcol*4+2)*512 + lane*8]); \
        short8 bl2 = *reinterpret_cast<const short8*>(&bufc[4096 + (wcol*4+2)*512 + lane*8]); \
        short8 bh3 = *reinterpret_cast<const short8*>(&bufc[(wcol*4+3)*512 + lane*8]); \
        short8 bl3 = *reinterpret_cast<const short8*>(&bufc[4096 + (wcol*4+3)*512 + lane*8]); \
        _Pragma("unroll")                                                           \
        for (int mi = 0; mi < 2; ++mi) {                                            \
            acc[mi][2] = __builtin_amdgcn_mfma_f32_16x16x32_bf16(UH[mi], bh2, acc[mi][2], 0, 0, 0); \
            acc[mi][2] = __builtin_amdgcn_mfma_f32_16x16x32_bf16(UH[mi], bl2, acc[mi][2], 0, 0, 0); \
            acc[mi][2] = __builtin_amdgcn_mfma_f32_16x16x32_bf16(UL[mi], bh2, acc[mi][2], 0, 0, 0); \
            acc[mi][3] = __builtin_amdgcn_mfma_f32_16x16x32_bf16(UH[mi], bh3, acc[mi][3], 0, 0, 0); \
            acc[mi][3] = __builtin_amdgcn_mfma_f32_16x16x32_bf16(UH[mi], bl3, acc[mi][3], 0, 0, 0); \
            acc[mi][3] = __builtin_amdgcn_mfma_f32_16x16x32_bf16(UL[mi], bh3, acc[mi][3], 0, 0, 0); \
        }                                                                           \
        __builtin_amdgcn_s_setprio(0);                                              \
    }

    // full step: issue t+2; vmcnt(12) drains A(t); compute; lgkm(0);
    // vmcnt(10) drains B(t+1); barrier (certify B(t+1) + free buf for rewrite)
    #define STEPF_(T, SLOT, UH, UL, WH, WL)                                         \
    {                                                                               \
        const size_t kk = (size_t)((T) + 2) * 512;                                  \
        ushort_t* bufw = &lds[((SLOT) + 2) % 3][0];                                 \
        gload16(bpH + kk, bufw + wid * 512);                                        \
        gload16(bpL + kk, bufw + 4096 + wid * 512);                                 \
        WH[0] = *reinterpret_cast<const short8*>(apH[0] + kk);                      \
        WH[1] = *reinterpret_cast<const short8*>(apH[1] + kk);                      \
        WL[0] = *reinterpret_cast<const short8*>(apL[0] + kk);                      \
        WL[1] = *reinterpret_cast<const short8*>(apL[1] + kk);                      \
        __builtin_amdgcn_sched_barrier(0);                                          \
        asm volatile("s_waitcnt vmcnt(12)" ::: "memory");                           \
        __builtin_amdgcn_sched_barrier(0);                                          \
        COMPUTE_(SLOT, UH, UL)                                                      \
        asm volatile("s_waitcnt lgkmcnt(0)" ::: "memory");                          \
        __builtin_amdgcn_sched_barrier(0);                                          \
        asm volatile("s_waitcnt vmcnt(10)" ::: "memory");                           \
        __builtin_amdgcn_sched_barrier(0);                                          \
        __builtin_amdgcn_s_barrier();                                               \
    }

    // tail steps: no issue
    #define STEPT_(SLOT, VM1, VM2, UH, UL)                                          \
    {                                                                               \
        asm volatile(VM1 ::: "memory");                                             \
        __builtin_amdgcn_sched_barrier(0);                                          \
        COMPUTE_(SLOT, UH, UL)                                                      \
        asm volatile("s_waitcnt lgkmcnt(0)" ::: "memory");                          \
        __builtin_amdgcn_sched_barrier(0);                                          \
        asm volatile(VM2 ::: "memory");                                             \
        __builtin_amdgcn_sched_barrier(0);                                          \
        __builtin_amdgcn_s_barrier();                                               \
    }

    for (int t = 0; t < KB - 2; t += 3) {
        STEPF_(t + 0, 0, aH0, aL0, aH2, aL2);
        STEPF_(t + 1, 1, aH1, aL1, aH0, aL0);
        STEPF_(t + 2, 2, aH2, aL2, aH1, aL1);
    }
    // KB % 3 == 2: tails use slots 0 then 1
    STEPT_(0, "s_waitcnt vmcnt(6)", "s_waitcnt vmcnt(4)", aH0, aL0);
    STEPT_(1, "s_waitcnt vmcnt(0)", "s_waitcnt vmcnt(0)", aH1, aL1);

    #undef STEPF_
    #undef STEPT_
    #undef COMPUTE_

    const float* be = bias + (size_t)e * N;
    if (MODE == 0) {
        #pragma unroll
        for (int mi = 0; mi < 2; ++mi) {
            const int g2 = G0 + wrow * 2 + mi;
            #pragma unroll
            for (int rg = 0; rg < 4; ++rg) {
                const int r15o = lkg * 4 + rg;
                #pragma unroll
                for (int ni = 0; ni < 4; ++ni) {
                    const int f = n0 + wcol * 64 + ni * 16 + l15;
                    float v = acc[mi][ni][rg] + be[f];
                    float u = 1.5957691216057308f * (v + 0.044715f * v * v * v);
                    v = v / (1.f + __expf(-u));
                    ushort_t h, l;
                    split_bf16(v, h, l);
                    size_t off = (((size_t)g2 * KBH + (f >> 5)) * 64
                                  + ((f >> 3) & 3) * 16 + r15o) * 8 + (f & 7);
                    outHh[off] = h;
                    outHl[off] = l;
                }
            }
        }
    } else {
        const int* lst = list + (size_t)e * T_;
        #pragma unroll
        for (int mi = 0; mi < 2; ++mi) {
            #pragma unroll
            for (int rg = 0; rg < 4; ++rg) {
                int rm = m0 + wrow * 32 + mi * 16 + lkg * 4 + rg;
                if (rm >= cnt) continue;
                int t = lst[rm];
                float gv = gate[t];
                float* crow = outF + (size_t)t * (size_t)N;
                #pragma unroll
                for (int ni = 0; ni < 4; ++ni) {
                    int col = n0 + wcol * 64 + ni * 16 + l15;
                    crow[col] = gv * (acc[mi][ni][rg] + be[col]);
                }
            }
        }
    }
}

// ---------------- tier-B fallback (round-2 proven path) ----------------

__global__ void k_convert_x(const float* __restrict__ x,
                            ushort_t* __restrict__ xh, ushort_t* __restrict__ xl) {
    size_t i = ((size_t)blockIdx.x * 256 + threadIdx.x) * 8;
    float4 a = *reinterpret_cast<const float4*>(x + i);
    float4 b = *reinterpret_cast<const float4*>(x + i + 4);
    float v[8] = { a.x, a.y, a.z, a.w, b.x, b.y, b.z, b.w };
    unsigned hw[4], lw[4];
    #pragma unroll
    for (int j = 0; j < 4; ++j) {
        ushort_t h0, l0, h1, l1;
        split_bf16(v[2*j], h0, l0);
        split_bf16(v[2*j+1], h1, l1);
        hw[j] = (unsigned)h0 | ((unsigned)h1 << 16);
        lw[j] = (unsigned)l0 | ((unsigned)l1 << 16);
    }
    *reinterpret_cast<uint4*>(xh + i) = make_uint4(hw[0], hw[1], hw[2], hw[3]);
    *reinterpret_cast<uint4*>(xl + i) = make_uint4(lw[0], lw[1], lw[2], lw[3]);
}

template<int MODE>
__global__ __launch_bounds__(256)
void k_gemm2(const ushort_t* __restrict__ Ah, const ushort_t* __restrict__ Al,
             const ushort_t* __restrict__ Bh, const ushort_t* __restrict__ Bl,
             const float* __restrict__ bias, float* __restrict__ outF,
             ushort_t* __restrict__ outHh, ushort_t* __restrict__ outHl,
             const int* __restrict__ list, const int* __restrict__ counts,
             const int* __restrict__ offs, const float* __restrict__ gate,
             int K, int N, int NT)
{
    const int e = blockIdx.z;
    const int cnt = counts[e];
    const int m0 = blockIdx.x * 128;
    if (m0 >= cnt) return;
    const int n0 = blockIdx.y * 128;
    const int hbase = offs[e];
    const int KB = K >> 5;
    const int tid = threadIdx.x, wid = tid >> 6, lane = tid & 63;
    const int l15 = lane & 15, lkg = lane >> 4;
    const int* lst = list + (size_t)e * T_;
    __shared__ __align__(16) ushort_t lds[16384];
    size_t a_rel[2], b_rel[2];
    #pragma unroll
    for (int i = 0; i < 2; ++i) {
        int rf = wid * 2 + i;
        int rm = m0 + rf * 16 + l15;
        int rr = rm < cnt ? rm : cnt - 1;
        size_t row = (MODE == 0) ? (size_t)lst[rr] : (size_t)(hbase + rr);
        a_rel[i] = row * (size_t)K + (size_t)lkg * 8;
        b_rel[i] = (((size_t)e * NT + (n0 >> 4) + rf) * (size_t)KB) * 512 + (size_t)lane * 8;
    }
    const int wr = wid >> 1, wc = wid & 1;
    f32x4 acc[4][4];
    #pragma unroll
    for (int i = 0; i < 4; ++i)
        #pragma unroll
        for (int j = 0; j < 4; ++j) acc[i][j] = (f32x4){0.f, 0.f, 0.f, 0.f};
    for (int kb = 0; kb < KB; ++kb) {
        __syncthreads();
        #pragma unroll
        for (int i = 0; i < 2; ++i) {
            int c = wid * 2 + i;
            gload16(Ah + a_rel[i] + (size_t)kb * 32, &lds[c * 512]);
            gload16(Al + a_rel[i] + (size_t)kb * 32, &lds[4096 + c * 512]);
            gload16(Bh + b_rel[i] + (size_t)kb * 512, &lds[8192 + c * 512]);
            gload16(Bl + b_rel[i] + (size_t)kb * 512, &lds[12288 + c * 512]);
        }
        __syncthreads();
        short8 ah[4], al[4], bh[4], bl[4];
        #pragma unroll
        for (int mi = 0; mi < 4; ++mi) {
            int rf = wr * 4 + mi;
            ah[mi] = *reinterpret_cast<const short8*>(&lds[rf * 512 + lane * 8]);
            al[mi] = *reinterpret_cast<const short8*>(&lds[4096 + rf * 512 + lane * 8]);
        }
        #pragma unroll
        for (int ni = 0; ni < 4; ++ni) {
            int nt = wc * 4 + ni;
            bh[ni] = *reinterpret_cast<const short8*>(&lds[8192 + nt * 512 + lane * 8]);
            bl[ni] = *reinterpret_cast<const short8*>(&lds[12288 + nt * 512 + lane * 8]);
        }
        #pragma unroll
        for (int mi = 0; mi < 4; ++mi)
            #pragma unroll
            for (int ni = 0; ni < 4; ++ni) {
                acc[mi][ni] = __builtin_amdgcn_mfma_f32_16x16x32_bf16(ah[mi], bh[ni], acc[mi][ni], 0, 0, 0);
                acc[mi][ni] = __builtin_amdgcn_mfma_f32_16x16x32_bf16(ah[mi], bl[ni], acc[mi][ni], 0, 0, 0);
                acc[mi][ni] = __builtin_amdgcn_mfma_f32_16x16x32_bf16(al[mi], bh[ni], acc[mi][ni], 0, 0, 0);
            }
    }
    const float* be = bias + (size_t)e * N;
    #pragma unroll
    for (int mi = 0; mi < 4; ++mi) {
        #pragma unroll
        for (int rg = 0; rg < 4; ++rg) {
            int rm = m0 + wr * 64 + mi * 16 + lkg * 4 + rg;
            if (rm >= cnt) continue;
            if (MODE == 0) {
                size_t rowb = (size_t)(hbase + rm) * (size_t)F_;
                #pragma unroll
                for (int ni = 0; ni < 4; ++ni) {
                    int col = n0 + wc * 64 + ni * 16 + l15;
                    float v = acc[mi][ni][rg] + be[col];
                    float u = 1.5957691216057308f * (v + 0.044715f * v * v * v);
                    v = v / (1.f + __expf(-u));
                    ushort_t h, l;
                    split_bf16(v, h, l);
                    outHh[rowb + col] = h;
                    outHl[rowb + col] = l;
                }
            } else {
                int t = lst[rm];
                float gv = gate[t];
                float* crow = outF + (size_t)t * (size_t)N;
                #pragma unroll
                for (int ni = 0; ni < 4; ++ni) {
                    int col = n0 + wc * 64 + ni * 16 + l15;
                    crow[col] = gv * (acc[mi][ni][rg] + be[col]);
                }
            }
        }
    }
}

// ---------------- launch ----------------

extern "C" void kernel_launch(void* const* d_in, const int* in_sizes, int n_in,
                              void* d_out, int out_size, void* d_ws, size_t ws_size,
                              hipStream_t stream) {
    const float* x   = (const float*)d_in[0];
    const float* rw  = (const float*)d_in[1];
    const float* w1  = (const float*)d_in[2];
    const float* b1  = (const float*)d_in[3];
    const float* w2  = (const float*)d_in[4];
    const float* b2  = (const float*)d_in[5];
    float* out = (float*)d_out;

    const size_t HCAP = (size_t)PCAP_ * F_;
    const size_t XCAP = (size_t)PCAP_ * D_;
    const size_t WCAP = (size_t)E_ * D_ * F_;
    const size_t misc = ((size_t)T_ * E_ + T_ + (size_t)E_ * T_) * 4 + 256;

    const size_t need_A = (2 * HCAP + 2 * XCAP + 2 * WCAP) * 2 + misc;   // ~246 MB
    const size_t hf = (size_t)T_ * F_;
    const size_t xd = (size_t)T_ * D_;
    const size_t need_B = (2 * hf + 2 * xd + 2 * WCAP) * 2 + misc;       // ~201 MB

    if (ws_size >= need_A) {
        ushort_t* hh  = (ushort_t*)d_ws;
        ushort_t* hl  = hh + HCAP;
        ushort_t* xh  = hl + HCAP;
        ushort_t* xl  = xh + XCAP;
        ushort_t* wph = xl + XCAP;
        ushort_t* wpl = wph + WCAP;
        float* r    = (float*)(wpl + WCAP);
        float* gate = r + (size_t)T_ * E_;
        int* list   = (int*)(gate + T_);
        int* counts = list + (size_t)E_ * T_;
        int* offs   = counts + E_;
        int* pbase  = offs + E_;

        k_router<<<T_ / 4, 256, 0, stream>>>(x, rw, r, counts);
        k_convert_w<<<dim3(F_ / 128, D_ / 32, E_), 256, 0, stream>>>(w1, wph, wpl, D_, F_);
        k_scan<<<B_ * E_, 64, 0, stream>>>(r);
        k_route<<<T_ / 256, 256, 0, stream>>>(r, gate, list, counts);
        k_offs<<<1, 64, 0, stream>>>(counts, offs, pbase);
        k_gather<<<GCAP_, 256, 0, stream>>>(x, list, counts, pbase, xh, xl);

        k_g8<0><<<dim3(T_ / 128, F_ / 128, E_), 512, 0, stream>>>(
            xh, xl, wph, wpl, b1, nullptr, hh, hl, list, counts, pbase, nullptr);
        k_convert_w<<<dim3(D_ / 128, F_ / 32, E_), 256, 0, stream>>>(w2, wph, wpl, F_, D_);
        k_g8<1><<<dim3(T_ / 128, D_ / 128, E_), 512, 0, stream>>>(
            hh, hl, wph, wpl, b2, out, nullptr, nullptr, list, counts, pbase, gate);
    } else if (ws_size >= need_B) {
        ushort_t* hh  = (ushort_t*)d_ws;
        ushort_t* hl  = hh + hf;
        ushort_t* xh  = hl + hf;
        ushort_t* xl  = xh + xd;
        ushort_t* wph = xl + xd;
        ushort_t* wpl = wph + WCAP;
        float* r    = (float*)(wpl + WCAP);
        float* gate = r + (size_t)T_ * E_;
        int* list   = (int*)(gate + T_);
        int* counts = list + (size_t)E_ * T_;
        int* offs   = counts + E_;
        int* pbase  = offs + E_;

        k_router<<<T_ / 4, 256, 0, stream>>>(x, rw, r, counts);
        k_convert_x<<<(int)(xd / 2048), 256, 0, stream>>>(x, xh, xl);
        k_convert_w<<<dim3(F_ / 128, D_ / 32, E_), 256, 0, stream>>>(w1, wph, wpl, D_, F_);
        k_scan<<<B_ * E_, 64, 0, stream>>>(r);
        k_route<<<T_ / 256, 256, 0, stream>>>(r, gate, list, counts);
        k_offs<<<1, 64, 0, stream>>>(counts, offs, pbase);

        k_gemm2<0><<<dim3(T_ / 128, F_ / 128, E_), 256, 0, stream>>>(
            xh, xl, wph, wpl, b1, nullptr, hh, hl, list, counts, offs, nullptr,
            D_, F_, F_ / 16);
        k_convert_w<<<dim3(D_ / 128, F_ / 32, E_), 256, 0, stream>>>(w2, wph, wpl, F_, D_);
        k_gemm2<1><<<dim3(T_ / 128, D_ / 128, E_), 256, 0, stream>>>(
            hh, hl, wph, wpl, b2, out, nullptr, nullptr, list, counts, offs, gate,
            F_, D_, D_ / 16);
    }
    // else: ws too small -> leave poison, fail loudly
}

// Round 9
// 941.146 us; speedup vs baseline: 1.1191x; 1.0010x over previous
//
#include <hip/hip_runtime.h>
#include <math.h>

#define B_ 4
#define S_ 2048
#define D_ 1024
#define F_ 4096
#define E_ 4
#define T_ (B_*S_)        // 8192 tokens
#define PCAP_ 8704        // max padded rows: 8192 + 4*127 rounded to 128
#define GCAP_ (PCAP_/16)  // 544 row-groups

typedef unsigned short ushort_t;
typedef __attribute__((ext_vector_type(8))) short short8;
typedef __attribute__((ext_vector_type(4))) float f32x4;

__device__ __forceinline__ ushort_t f2bf_rne(float f) {
    unsigned u = __float_as_uint(f);
    unsigned r = 0x7FFFu + ((u >> 16) & 1u);
    u += r;
    return (ushort_t)(u >> 16);
}

__device__ __forceinline__ void gload16(const void* g, void* l) {
    __builtin_amdgcn_global_load_lds(
        (const __attribute__((address_space(1))) unsigned int*)g,
        (__attribute__((address_space(3))) unsigned int*)l, 16, 0, 0);
}

// ---------------- routing ----------------

__global__ void k_router(const float* __restrict__ x, const float* __restrict__ rw,
                         float* __restrict__ r, int* __restrict__ counts) {
    if (blockIdx.x == 0 && threadIdx.x < E_) counts[threadIdx.x] = 0;
    int wid = blockIdx.x * 4 + (threadIdx.x >> 6);
    int lane = threadIdx.x & 63;
    const float* xr = x + (size_t)wid * D_;
    float a0 = 0.f, a1 = 0.f, a2 = 0.f, a3 = 0.f;
    for (int i = lane; i < D_; i += 64) {
        float xv = xr[i];
        float4 w = reinterpret_cast<const float4*>(rw)[i];
        a0 += xv * w.x; a1 += xv * w.y; a2 += xv * w.z; a3 += xv * w.w;
    }
    for (int off = 32; off; off >>= 1) {
        a0 += __shfl_down(a0, off, 64);
        a1 += __shfl_down(a1, off, 64);
        a2 += __shfl_down(a2, off, 64);
        a3 += __shfl_down(a3, off, 64);
    }
    if (lane == 0) {
        float4 v; v.x = a0; v.y = a1; v.z = a2; v.w = a3;
        reinterpret_cast<float4*>(r)[wid] = v;
    }
}

__global__ void k_scan(float* __restrict__ r) {
    int b = blockIdx.x >> 2, e = blockIdx.x & 3;
    int lane = threadIdx.x;
    float carry = 0.f;
    for (int c = 0; c < S_ / 64; ++c) {
        int s = c * 64 + lane;
        float* p = r + ((size_t)(b * S_ + s)) * E_ + e;
        float v = *p;
        #pragma unroll
        for (int off = 1; off < 64; off <<= 1) {
            float u = __shfl_up(v, off, 64);
            if (lane >= off) v += u;
        }
        v += carry;
        *p = v;
        carry = __shfl(v, 63, 64);
    }
}

__global__ void k_route(const float* __restrict__ r, float* __restrict__ gate,
                        int* __restrict__ list, int* __restrict__ counts) {
    int t = blockIdx.x * blockDim.x + threadIdx.x;
    if (t >= T_) return;
    int s = t & (S_ - 1);
    float4 l4 = reinterpret_cast<const float4*>(r)[t];
    float inv = 1.f / (float)(s + 1);
    float l[4] = { l4.x * inv, l4.y * inv, l4.z * inv, l4.w * inv };
    int best = 0; float m = l[0];
    #pragma unroll
    for (int e = 1; e < 4; ++e) if (l[e] > m) { m = l[e]; best = e; }
    float sum = 0.f;
    #pragma unroll
    for (int e = 0; e < 4; ++e) sum += expf(l[e] - m);
    gate[t] = 1.f / sum;
    int pos = atomicAdd(&counts[best], 1);
    list[best * T_ + pos] = t;
}

__global__ void k_offs(const int* __restrict__ counts, int* __restrict__ offs,
                       int* __restrict__ pbase) {
    if (threadIdx.x == 0) {
        int a = 0, p = 0;
        pbase[0] = 0;
        for (int e = 0; e < E_; ++e) {
            offs[e] = a; a += counts[e];
            p += (counts[e] + 127) & ~127;
            pbase[e + 1] = p;
        }
    }
}

// ---------------- gather x into padded expert order, frag-tiled bf16 ----------------
// Plane layout: [g16][kb=K/32][lane64=kg*16+r15][8], elem k = kb*32+kg*8+j.
__global__ __launch_bounds__(256)
void k_gather1(const float* __restrict__ x, const int* __restrict__ list,
               const int* __restrict__ counts, const int* __restrict__ pbase,
               ushort_t* __restrict__ Xb)
{
    constexpr int KB = D_ / 32;
    const int g = blockIdx.x;
    const int r15 = threadIdx.x & 15;
    const int kq = threadIdx.x >> 4;
    const int v = g * 16 + r15;
    int e = 0;
    #pragma unroll
    for (int i = 0; i < E_; ++i) if (v >= pbase[i + 1]) e = i + 1;
    int token = -1;
    if (e < E_) {
        int local = v - pbase[e];
        if (local < counts[e]) token = list[e * T_ + local];
    }
    const float* xr = x + (size_t)(token >= 0 ? token : 0) * D_;
    #pragma unroll
    for (int c8 = 0; c8 < 8; ++c8) {
        const int k = kq * 64 + c8 * 8;
        float vv[8];
        if (token >= 0) {
            float4 u0 = *reinterpret_cast<const float4*>(xr + k);
            float4 u1 = *reinterpret_cast<const float4*>(xr + k + 4);
            vv[0]=u0.x; vv[1]=u0.y; vv[2]=u0.z; vv[3]=u0.w;
            vv[4]=u1.x; vv[5]=u1.y; vv[6]=u1.z; vv[7]=u1.w;
        } else {
            #pragma unroll
            for (int j = 0; j < 8; ++j) vv[j] = 0.f;
        }
        unsigned hw[4];
        #pragma unroll
        for (int j = 0; j < 4; ++j)
            hw[j] = (unsigned)f2bf_rne(vv[2*j]) | ((unsigned)f2bf_rne(vv[2*j+1]) << 16);
        size_t off = (((size_t)g * KB + (k >> 5)) * 64 + ((k >> 3) & 3) * 16 + r15) * 8;
        *reinterpret_cast<uint4*>(Xb + off) = make_uint4(hw[0], hw[1], hw[2], hw[3]);
    }
}

// ---------------- weight conversion to frag-order bf16 plane ----------------
// [e][nt=N/16][kb=K/32][64][8]; grid (N/128, K/32, E), 256 thr.
__global__ __launch_bounds__(256)
void k_convert_w1(const float* __restrict__ W, ushort_t* __restrict__ P,
                  int K, int N) {
    const int e = blockIdx.z;
    const int n0 = blockIdx.x * 128;
    const int k0 = blockIdx.y * 32;
    const int kb = blockIdx.y;
    const int NT = N >> 4, KB = K >> 5;
    __shared__ float lf[32 * 128];
    const float* We = W + (size_t)e * K * N;
    const int tid = threadIdx.x;
    #pragma unroll
    for (int i = 0; i < 4; ++i) {
        int q = i * 256 + tid;
        int k = q >> 5, c4 = q & 31;
        float4 v = *reinterpret_cast<const float4*>(We + (size_t)(k0 + k) * N + n0 + c4 * 4);
        *reinterpret_cast<float4*>(lf + k * 128 + c4 * 4) = v;
    }
    __syncthreads();
    #pragma unroll
    for (int p = 0; p < 2; ++p) {
        int q = p * 256 + tid;
        int n = q & 127, kg = q >> 7;
        unsigned hw[4];
        #pragma unroll
        for (int j = 0; j < 8; j += 2) {
            float f0 = lf[(kg * 8 + j) * 128 + n];
            float f1 = lf[(kg * 8 + j + 1) * 128 + n];
            hw[j >> 1] = (unsigned)f2bf_rne(f0) | ((unsigned)f2bf_rne(f1) << 16);
        }
        size_t off = ((((size_t)e * NT + ((n0 + n) >> 4)) * KB + kb) * 64
                      + (kg * 16 + (n & 15))) * 8;
        *reinterpret_cast<uint4*>(P + off) = make_uint4(hw[0], hw[1], hw[2], hw[3]);
    }
}

// ---------------- main grouped GEMMs: single-pass bf16 flatmm ----------------
// MODE 0: h(frag-order bf16) = gelu(Xg @ w1 + b1)   K=1024, N=4096
// MODE 1: out(scatter,f32)   = gate*(h @ w2 + b2)   K=4096, N=1024
// 8 waves (512 thr), block tile 128(M) x 256(N), BK=64 per step.
// Wave tile 64x64: wrow=wid>>2 (0..1), wcol=wid&3 (0..3).
// A: global->reg, double set (A0/A1), 8 short8 loads/step.
// B: gload16 to LDS, dbuf 2x32KB; wave stages 4 chunks (1KB each)/step.
// Queue (issue order B(4) then A(8) = 12/step):
//   step t: issue t+1 -> vmcnt(12)=drain A(t) -> ds_read+MFMA (kk=0,1)
//           -> lgkm(0) -> vmcnt(8)=drain B(t+1) -> s_barrier.
template<int MODE>
__global__ __launch_bounds__(512, 3)
void k_g9(const ushort_t* __restrict__ A, const ushort_t* __restrict__ Bw,
          const float* __restrict__ bias, float* __restrict__ outF,
          ushort_t* __restrict__ outH,
          const int* __restrict__ list, const int* __restrict__ counts,
          const int* __restrict__ pbase, const float* __restrict__ gate)
{
    constexpr int K  = (MODE == 0) ? D_ : F_;
    constexpr int N  = (MODE == 0) ? F_ : D_;
    constexpr int KB32 = K / 32;
    constexpr int STEPS = K / 64;         // 16 or 64 (even)
    constexpr int NT = N / 16;
    constexpr int KBH = F_ / 32;

    const int e = blockIdx.z;
    const int cnt = counts[e];
    const int m0 = blockIdx.x * 128;
    if (m0 >= cnt) return;
    const int n0 = blockIdx.y * 256;
    const int pb = pbase[e];
    const int tid = threadIdx.x, wid = tid >> 6, lane = tid & 63;
    const int l15 = lane & 15, lkg = lane >> 4;
    const int wrow = wid >> 2, wcol = wid & 3;
    const int G0 = (pb + m0) >> 4;

    // 2 buffers x 32 chunks x 512 shorts (chunk c = nt*2+kk) = 2 x 32 KB
    __shared__ __align__(16) ushort_t lds[2][16384];

    const ushort_t* apA[4];
    #pragma unroll
    for (int mi = 0; mi < 4; ++mi)
        apA[mi] = A + ((size_t)(G0 + wrow * 4 + mi) * KB32) * 512 + (size_t)lane * 8;
    const ushort_t* bsrc[4];
    #pragma unroll
    for (int j = 0; j < 4; ++j)
        bsrc[j] = Bw + (((size_t)e * NT + (n0 >> 4) + wid * 2 + (j >> 1)) * KB32) * 512
                     + (size_t)(j & 1) * 512 + (size_t)lane * 8;

    f32x4 acc[4][4];
    #pragma unroll
    for (int i = 0; i < 4; ++i)
        #pragma unroll
        for (int j = 0; j < 4; ++j) acc[i][j] = (f32x4){0.f, 0.f, 0.f, 0.f};

    short8 A0[8], A1[8];

    // ---- prologue: issue B(0)[4], A(0)[8]; drain B(0); barrier ----
    #pragma unroll
    for (int j = 0; j < 4; ++j)
        gload16(bsrc[j], &lds[0][(wid * 4 + j) * 512]);
    __builtin_amdgcn_sched_barrier(0);
    #pragma unroll
    for (int mi = 0; mi < 4; ++mi) {
        A0[mi * 2 + 0] = *reinterpret_cast<const short8*>(apA[mi]);
        A0[mi * 2 + 1] = *reinterpret_cast<const short8*>(apA[mi] + 512);
    }
    __builtin_amdgcn_sched_barrier(0);
    asm volatile("s_waitcnt vmcnt(8)" ::: "memory");
    __builtin_amdgcn_sched_barrier(0);
    __builtin_amdgcn_s_barrier();

    #define COMPUTE_(P, U)                                                          \
    {                                                                               \
        const ushort_t* lb = &lds[(P)][0];                                          \
        __builtin_amdgcn_s_setprio(1);                                              \
        short8 bv0[4];                                                              \
        _Pragma("unroll")                                                           \
        for (int ni = 0; ni < 4; ++ni)                                              \
            bv0[ni] = *reinterpret_cast<const short8*>(&lb[(wcol * 8 + ni * 2 + 0) * 512 + lane * 8]); \
        _Pragma("unroll")                                                           \
        for (int mi = 0; mi < 4; ++mi)                                              \
            _Pragma("unroll")                                                       \
            for (int ni = 0; ni < 4; ++ni)                                          \
                acc[mi][ni] = __builtin_amdgcn_mfma_f32_16x16x32_bf16(U[mi * 2 + 0], bv0[ni], acc[mi][ni], 0, 0, 0); \
        short8 bv1[4];                                                              \
        _Pragma("unroll")                                                           \
        for (int ni = 0; ni < 4; ++ni)                                              \
            bv1[ni] = *reinterpret_cast<const short8*>(&lb[(wcol * 8 + ni * 2 + 1) * 512 + lane * 8]); \
        _Pragma("unroll")                                                           \
        for (int mi = 0; mi < 4; ++mi)                                              \
            _Pragma("unroll")                                                       \
            for (int ni = 0; ni < 4; ++ni)                                          \
                acc[mi][ni] = __builtin_amdgcn_mfma_f32_16x16x32_bf16(U[mi * 2 + 1], bv1[ni], acc[mi][ni], 0, 0, 0); \
        __builtin_amdgcn_s_setprio(0);                                              \
    }

    #define STEPF_(T, P, U, W)                                                      \
    {                                                                               \
        ushort_t* lw = &lds[(P) ^ 1][0];                                            \
        const size_t so = (size_t)((T) + 1) * 1024;                                 \
        _Pragma("unroll")                                                           \
        for (int j = 0; j < 4; ++j)                                                 \
            gload16(bsrc[j] + so, lw + (wid * 4 + j) * 512);                        \
        __builtin_amdgcn_sched_barrier(0);                                          \
        _Pragma("unroll")                                                           \
        for (int mi = 0; mi < 4; ++mi) {                                            \
            W[mi * 2 + 0] = *reinterpret_cast<const short8*>(apA[mi] + so);         \
            W[mi * 2 + 1] = *reinterpret_cast<const short8*>(apA[mi] + so + 512);   \
        }                                                                           \
        __builtin_amdgcn_sched_barrier(0);                                          \
        asm volatile("s_waitcnt vmcnt(12)" ::: "memory");                           \
        __builtin_amdgcn_sched_barrier(0);                                          \
        COMPUTE_(P, U)                                                              \
        asm volatile("s_waitcnt lgkmcnt(0)" ::: "memory");                          \
        __builtin_amdgcn_sched_barrier(0);                                          \
        asm volatile("s_waitcnt vmcnt(8)" ::: "memory");                            \
        __builtin_amdgcn_sched_barrier(0);                                          \
        __builtin_amdgcn_s_barrier();                                               \
    }

    #define STEPT_(P, U)                                                            \
    {                                                                               \
        asm volatile("s_waitcnt vmcnt(0)" ::: "memory");                            \
        __builtin_amdgcn_sched_barrier(0);                                          \
        COMPUTE_(P, U)                                                              \
    }

    for (int t = 0; t + 2 < STEPS; t += 2) {
        STEPF_(t, 0, A0, A1);
        STEPF_(t + 1, 1, A1, A0);
    }
    STEPF_(STEPS - 2, 0, A0, A1);
    STEPT_(1, A1);

    #undef STEPF_
    #undef STEPT_
    #undef COMPUTE_

    const float* be = bias + (size_t)e * N;
    if (MODE == 0) {
        #pragma unroll
        for (int mi = 0; mi < 4; ++mi) {
            const int g2 = G0 + wrow * 4 + mi;
            #pragma unroll
            for (int rg = 0; rg < 4; ++rg) {
                const int r15o = lkg * 4 + rg;
                #pragma unroll
                for (int ni = 0; ni < 4; ++ni) {
                    const int f = n0 + wcol * 64 + ni * 16 + l15;
                    float v = acc[mi][ni][rg] + be[f];
                    float u = 1.5957691216057308f * (v + 0.044715f * v * v * v);
                    v = v / (1.f + __expf(-u));
                    size_t off = (((size_t)g2 * KBH + (f >> 5)) * 64
                                  + ((f >> 3) & 3) * 16 + r15o) * 8 + (f & 7);
                    outH[off] = f2bf_rne(v);
                }
            }
        }
    } else {
        const int* lst = list + (size_t)e * T_;
        #pragma unroll
        for (int mi = 0; mi < 4; ++mi) {
            #pragma unroll
            for (int rg = 0; rg < 4; ++rg) {
                int rm = m0 + wrow * 64 + mi * 16 + lkg * 4 + rg;
                if (rm >= cnt) continue;
                int t = lst[rm];
                float gv = gate[t];
                float* crow = outF + (size_t)t * (size_t)N;
                #pragma unroll
                for (int ni = 0; ni < 4; ++ni) {
                    int col = n0 + wcol * 64 + ni * 16 + l15;
                    crow[col] = gv * (acc[mi][ni][rg] + be[col]);
                }
            }
        }
    }
}

// ---------------- launch ----------------

extern "C" void kernel_launch(void* const* d_in, const int* in_sizes, int n_in,
                              void* d_out, int out_size, void* d_ws, size_t ws_size,
                              hipStream_t stream) {
    const float* x   = (const float*)d_in[0];
    const float* rw  = (const float*)d_in[1];
    const float* w1  = (const float*)d_in[2];
    const float* b1  = (const float*)d_in[3];
    const float* w2  = (const float*)d_in[4];
    const float* b2  = (const float*)d_in[5];
    float* out = (float*)d_out;

    const size_t HCAP = (size_t)PCAP_ * F_;     // 35.65M shorts
    const size_t XCAP = (size_t)PCAP_ * D_;     // 8.91M shorts
    const size_t WCAP = (size_t)E_ * D_ * F_;   // 16.78M shorts
    const size_t misc = ((size_t)T_ * E_ + T_ + (size_t)E_ * T_) * 4 + 256;
    const size_t need = (HCAP + XCAP + WCAP) * 2 + misc;   // ~123 MB

    if (ws_size < need) return;  // fail loudly (ws proven >= 246MB in prior rounds)

    ushort_t* hB = (ushort_t*)d_ws;
    ushort_t* xB = hB + HCAP;
    ushort_t* wB = xB + XCAP;
    float* r    = (float*)(wB + WCAP);
    float* gate = r + (size_t)T_ * E_;
    int* list   = (int*)(gate + T_);
    int* counts = list + (size_t)E_ * T_;
    int* offs   = counts + E_;
    int* pbase  = offs + E_;

    k_router<<<T_ / 4, 256, 0, stream>>>(x, rw, r, counts);
    k_convert_w1<<<dim3(F_ / 128, D_ / 32, E_), 256, 0, stream>>>(w1, wB, D_, F_);
    k_scan<<<B_ * E_, 64, 0, stream>>>(r);
    k_route<<<T_ / 256, 256, 0, stream>>>(r, gate, list, counts);
    k_offs<<<1, 64, 0, stream>>>(counts, offs, pbase);
    k_gather1<<<GCAP_, 256, 0, stream>>>(x, list, counts, pbase, xB);

    k_g9<0><<<dim3(T_ / 128, F_ / 256, E_), 512, 0, stream>>>(
        xB, wB, b1, nullptr, hB, list, counts, pbase, nullptr);
    k_convert_w1<<<dim3(D_ / 128, F_ / 32, E_), 256, 0, stream>>>(w2, wB, F_, D_);
    k_g9<1><<<dim3(T_ / 128, D_ / 256, E_), 512, 0, stream>>>(
        hB, wB, b2, out, nullptr, list, counts, pbase, gate);
}

// Round 10
// 711.631 us; speedup vs baseline: 1.4800x; 1.3225x over previous
//
#include <hip/hip_runtime.h>
#include <math.h>

#define B_ 4
#define S_ 2048
#define D_ 1024
#define F_ 4096
#define E_ 4
#define T_ (B_*S_)        // 8192 tokens
#define PCAP_ 9216        // max padded rows: 8192 + 4*255 rounded up (256-pad)
#define GCAP_ (PCAP_/16)  // 576 row-groups

typedef unsigned short ushort_t;
typedef __attribute__((ext_vector_type(8))) short short8;
typedef __attribute__((ext_vector_type(4))) float f32x4;

__device__ __forceinline__ ushort_t f2bf_rne(float f) {
    unsigned u = __float_as_uint(f);
    unsigned r = 0x7FFFu + ((u >> 16) & 1u);
    u += r;
    return (ushort_t)(u >> 16);
}

__device__ __forceinline__ void gload16(const void* g, void* l) {
    __builtin_amdgcn_global_load_lds(
        (const __attribute__((address_space(1))) unsigned int*)g,
        (__attribute__((address_space(3))) unsigned int*)l, 16, 0, 0);
}

// ---------------- routing ----------------

__global__ void k_router(const float* __restrict__ x, const float* __restrict__ rw,
                         float* __restrict__ r, int* __restrict__ counts) {
    if (blockIdx.x == 0 && threadIdx.x < E_) counts[threadIdx.x] = 0;
    int wid = blockIdx.x * 4 + (threadIdx.x >> 6);
    int lane = threadIdx.x & 63;
    const float* xr = x + (size_t)wid * D_;
    float a0 = 0.f, a1 = 0.f, a2 = 0.f, a3 = 0.f;
    for (int i = lane; i < D_; i += 64) {
        float xv = xr[i];
        float4 w = reinterpret_cast<const float4*>(rw)[i];
        a0 += xv * w.x; a1 += xv * w.y; a2 += xv * w.z; a3 += xv * w.w;
    }
    for (int off = 32; off; off >>= 1) {
        a0 += __shfl_down(a0, off, 64);
        a1 += __shfl_down(a1, off, 64);
        a2 += __shfl_down(a2, off, 64);
        a3 += __shfl_down(a3, off, 64);
    }
    if (lane == 0) {
        float4 v; v.x = a0; v.y = a1; v.z = a2; v.w = a3;
        reinterpret_cast<float4*>(r)[wid] = v;
    }
}

__global__ void k_scan(float* __restrict__ r) {
    int b = blockIdx.x >> 2, e = blockIdx.x & 3;
    int lane = threadIdx.x;
    float carry = 0.f;
    for (int c = 0; c < S_ / 64; ++c) {
        int s = c * 64 + lane;
        float* p = r + ((size_t)(b * S_ + s)) * E_ + e;
        float v = *p;
        #pragma unroll
        for (int off = 1; off < 64; off <<= 1) {
            float u = __shfl_up(v, off, 64);
            if (lane >= off) v += u;
        }
        v += carry;
        *p = v;
        carry = __shfl(v, 63, 64);
    }
}

__global__ void k_route(const float* __restrict__ r, float* __restrict__ gate,
                        int* __restrict__ list, int* __restrict__ counts) {
    int t = blockIdx.x * blockDim.x + threadIdx.x;
    if (t >= T_) return;
    int s = t & (S_ - 1);
    float4 l4 = reinterpret_cast<const float4*>(r)[t];
    float inv = 1.f / (float)(s + 1);
    float l[4] = { l4.x * inv, l4.y * inv, l4.z * inv, l4.w * inv };
    int best = 0; float m = l[0];
    #pragma unroll
    for (int e = 1; e < 4; ++e) if (l[e] > m) { m = l[e]; best = e; }
    float sum = 0.f;
    #pragma unroll
    for (int e = 0; e < 4; ++e) sum += expf(l[e] - m);
    gate[t] = 1.f / sum;
    int pos = atomicAdd(&counts[best], 1);
    list[best * T_ + pos] = t;
}

__global__ void k_offs(const int* __restrict__ counts, int* __restrict__ offs,
                       int* __restrict__ pbase) {
    if (threadIdx.x == 0) {
        int a = 0, p = 0;
        pbase[0] = 0;
        for (int e = 0; e < E_; ++e) {
            offs[e] = a; a += counts[e];
            p += (counts[e] + 255) & ~255;   // 256-row padding (tile = 256 rows)
            pbase[e + 1] = p;
        }
    }
}

// ---------------- gather x into padded expert order, frag-tiled bf16 ----------------
// Plane layout: [g16][kb=K/32][lane64=kg*16+r15][8], elem k = kb*32+kg*8+j.
__global__ __launch_bounds__(256)
void k_gather1(const float* __restrict__ x, const int* __restrict__ list,
               const int* __restrict__ counts, const int* __restrict__ pbase,
               ushort_t* __restrict__ Xb)
{
    constexpr int KB = D_ / 32;
    const int g = blockIdx.x;
    const int r15 = threadIdx.x & 15;
    const int kq = threadIdx.x >> 4;
    const int v = g * 16 + r15;
    int e = 0;
    #pragma unroll
    for (int i = 0; i < E_; ++i) if (v >= pbase[i + 1]) e = i + 1;
    int token = -1;
    if (e < E_) {
        int local = v - pbase[e];
        if (local < counts[e]) token = list[e * T_ + local];
    }
    const float* xr = x + (size_t)(token >= 0 ? token : 0) * D_;
    #pragma unroll
    for (int c8 = 0; c8 < 8; ++c8) {
        const int k = kq * 64 + c8 * 8;
        float vv[8];
        if (token >= 0) {
            float4 u0 = *reinterpret_cast<const float4*>(xr + k);
            float4 u1 = *reinterpret_cast<const float4*>(xr + k + 4);
            vv[0]=u0.x; vv[1]=u0.y; vv[2]=u0.z; vv[3]=u0.w;
            vv[4]=u1.x; vv[5]=u1.y; vv[6]=u1.z; vv[7]=u1.w;
        } else {
            #pragma unroll
            for (int j = 0; j < 8; ++j) vv[j] = 0.f;
        }
        unsigned hw[4];
        #pragma unroll
        for (int j = 0; j < 4; ++j)
            hw[j] = (unsigned)f2bf_rne(vv[2*j]) | ((unsigned)f2bf_rne(vv[2*j+1]) << 16);
        size_t off = (((size_t)g * KB + (k >> 5)) * 64 + ((k >> 3) & 3) * 16 + r15) * 8;
        *reinterpret_cast<uint4*>(Xb + off) = make_uint4(hw[0], hw[1], hw[2], hw[3]);
    }
}

// ---------------- weight conversion to frag-order bf16 plane ----------------
__global__ __launch_bounds__(256)
void k_convert_w1(const float* __restrict__ W, ushort_t* __restrict__ P,
                  int K, int N) {
    const int e = blockIdx.z;
    const int n0 = blockIdx.x * 128;
    const int k0 = blockIdx.y * 32;
    const int kb = blockIdx.y;
    const int NT = N >> 4, KB = K >> 5;
    __shared__ float lf[32 * 128];
    const float* We = W + (size_t)e * K * N;
    const int tid = threadIdx.x;
    #pragma unroll
    for (int i = 0; i < 4; ++i) {
        int q = i * 256 + tid;
        int k = q >> 5, c4 = q & 31;
        float4 v = *reinterpret_cast<const float4*>(We + (size_t)(k0 + k) * N + n0 + c4 * 4);
        *reinterpret_cast<float4*>(lf + k * 128 + c4 * 4) = v;
    }
    __syncthreads();
    #pragma unroll
    for (int p = 0; p < 2; ++p) {
        int q = p * 256 + tid;
        int n = q & 127, kg = q >> 7;
        unsigned hw[4];
        #pragma unroll
        for (int j = 0; j < 8; j += 2) {
            float f0 = lf[(kg * 8 + j) * 128 + n];
            float f1 = lf[(kg * 8 + j + 1) * 128 + n];
            hw[j >> 1] = (unsigned)f2bf_rne(f0) | ((unsigned)f2bf_rne(f1) << 16);
        }
        size_t off = ((((size_t)e * NT + ((n0 + n) >> 4)) * KB + kb) * 64
                      + (kg * 16 + (n & 15))) * 8;
        *reinterpret_cast<uint4*>(P + off) = make_uint4(hw[0], hw[1], hw[2], hw[3]);
    }
}

// ---------------- main grouped GEMMs: 256-tile 2-phase (m248 recipe) ----------------
// MODE 0: h(frag-order bf16) = gelu(Xg @ w1 + b1)  K=1024, N=4096, BN=256
// MODE 1: out(scatter,f32)   = gate*(h @ w2 + b2)  K=4096, N=1024, BN=128
// 8 waves (512 thr). Block tile 256(M) x BN, BK=64/step. Wave grid 2Mx4N ->
// wave tile 128 x BN/4. A and B staged frag-order via gload16 into dbuf LDS.
// Per step: STAGE(buf^1, t+1) -> compute buf (24 ds_read + 64 MFMA) ->
// __syncthreads() (drains vmcnt+lgkm: next buf certified, cur freed). One
// barrier per step; compute phase (~1200cy) covers the staged-load latency.
template<int MODE>
__global__ __launch_bounds__(512)
void k_gA(const ushort_t* __restrict__ A, const ushort_t* __restrict__ Bw,
          const float* __restrict__ bias, float* __restrict__ outF,
          ushort_t* __restrict__ outH,
          const int* __restrict__ list, const int* __restrict__ counts,
          const int* __restrict__ pbase, const float* __restrict__ gate)
{
    constexpr int K    = (MODE == 0) ? D_ : F_;
    constexpr int N    = (MODE == 0) ? F_ : D_;
    constexpr int BN   = (MODE == 0) ? 256 : 128;
    constexpr int NI   = BN / 64;         // frags per wave in N: 4 or 2
    constexpr int STEPS = K / 64;         // 16 or 64
    constexpr int KB32 = K / 32;
    constexpr int NT   = N / 16;
    constexpr int KBH  = F_ / 32;
    constexpr int ACH  = 32;              // A chunks (256 rows x 64k) of 1KB
    constexpr int BCH  = (BN / 16) * 2;   // B chunks: 32 or 16
    constexpr int BPW  = BCH / 8;         // B chunks per wave: 4 or 2
    constexpr int LSZ  = (ACH + BCH) * 512;  // shorts per buffer

    const int e = blockIdx.z;
    const int cnt = counts[e];
    const int m0 = blockIdx.x * 256;
    if (m0 >= cnt) return;
    const int n0 = blockIdx.y * BN;
    const int pb = pbase[e];
    const int tid = threadIdx.x, wid = tid >> 6, lane = tid & 63;
    const int l15 = lane & 15, lkg = lane >> 4;
    const int wr = wid >> 2, wc = wid & 3;      // 2M x 4N wave grid
    const int G0 = (pb + m0) >> 4;

    __shared__ __align__(16) ushort_t lds[2][LSZ];

    // staging source pointers (step offset = t*1024 shorts)
    const ushort_t* aP[4];
    #pragma unroll
    for (int j = 0; j < 4; ++j) {
        const int c = wid * 4 + j;               // A chunk 0..31
        aP[j] = A + ((size_t)(G0 + (c >> 1)) * KB32 + (c & 1)) * 512 + (size_t)lane * 8;
    }
    const ushort_t* bP[BPW];
    #pragma unroll
    for (int j = 0; j < BPW; ++j) {
        const int c = wid * BPW + j;             // B chunk 0..BCH-1
        bP[j] = Bw + (((size_t)e * NT + (n0 >> 4) + (c >> 1)) * KB32 + (c & 1)) * 512
                   + (size_t)lane * 8;
    }

    f32x4 acc[8][NI];
    #pragma unroll
    for (int i = 0; i < 8; ++i)
        #pragma unroll
        for (int j = 0; j < NI; ++j) acc[i][j] = (f32x4){0.f, 0.f, 0.f, 0.f};

    // ---- prologue: stage tile 0 into buf 0 ----
    #pragma unroll
    for (int j = 0; j < 4; ++j)
        gload16(aP[j], &lds[0][(wid * 4 + j) * 512]);
    #pragma unroll
    for (int j = 0; j < BPW; ++j)
        gload16(bP[j], &lds[0][(ACH + wid * BPW + j) * 512]);
    __syncthreads();

    int cur = 0;
    for (int t = 0; t < STEPS; ++t) {
        // ---- issue prefetch of tile t+1 into buf[cur^1] ----
        if (t + 1 < STEPS) {
            const size_t so = (size_t)(t + 1) * 1024;
            ushort_t* L = &lds[cur ^ 1][0];
            #pragma unroll
            for (int j = 0; j < 4; ++j)
                gload16(aP[j] + so, L + (wid * 4 + j) * 512);
            #pragma unroll
            for (int j = 0; j < BPW; ++j)
                gload16(bP[j] + so, L + (ACH + wid * BPW + j) * 512);
        }
        // ---- compute tile t from buf[cur] ----
        const ushort_t* L = &lds[cur][0];
        __builtin_amdgcn_s_setprio(1);
        #pragma unroll
        for (int kk = 0; kk < 2; ++kk) {
            short8 av[8];
            #pragma unroll
            for (int mi = 0; mi < 8; ++mi)
                av[mi] = *reinterpret_cast<const short8*>(
                    &L[((wr * 8 + mi) * 2 + kk) * 512 + lane * 8]);
            short8 bv[NI];
            #pragma unroll
            for (int ni = 0; ni < NI; ++ni)
                bv[ni] = *reinterpret_cast<const short8*>(
                    &L[(ACH + (wc * NI + ni) * 2 + kk) * 512 + lane * 8]);
            #pragma unroll
            for (int mi = 0; mi < 8; ++mi)
                #pragma unroll
                for (int ni = 0; ni < NI; ++ni)
                    acc[mi][ni] = __builtin_amdgcn_mfma_f32_16x16x32_bf16(
                        av[mi], bv[ni], acc[mi][ni], 0, 0, 0);
        }
        __builtin_amdgcn_s_setprio(0);
        // one barrier per step: drains vmcnt (t+1 landed) + lgkm; frees cur.
        __syncthreads();
        cur ^= 1;
    }

    const float* be = bias + (size_t)e * N;
    if (MODE == 0) {
        #pragma unroll
        for (int mi = 0; mi < 8; ++mi) {
            const int g2 = G0 + wr * 8 + mi;
            #pragma unroll
            for (int rg = 0; rg < 4; ++rg) {
                const int r15o = lkg * 4 + rg;
                #pragma unroll
                for (int ni = 0; ni < NI; ++ni) {
                    const int f = n0 + wc * 64 + ni * 16 + l15;
                    float v = acc[mi][ni][rg] + be[f];
                    float u = 1.5957691216057308f * (v + 0.044715f * v * v * v);
                    v = v / (1.f + __expf(-u));
                    size_t off = (((size_t)g2 * KBH + (f >> 5)) * 64
                                  + ((f >> 3) & 3) * 16 + r15o) * 8 + (f & 7);
                    outH[off] = f2bf_rne(v);
                }
            }
        }
    } else {
        const int* lst = list + (size_t)e * T_;
        #pragma unroll
        for (int mi = 0; mi < 8; ++mi) {
            #pragma unroll
            for (int rg = 0; rg < 4; ++rg) {
                int rm = m0 + wr * 128 + mi * 16 + lkg * 4 + rg;
                if (rm >= cnt) continue;
                int t = lst[rm];
                float gv = gate[t];
                float* crow = outF + (size_t)t * (size_t)N;
                #pragma unroll
                for (int ni = 0; ni < NI; ++ni) {
                    int col = n0 + wc * 32 * (NI == 2 ? 1 : 2) + ni * 16 + l15;
                    crow[col] = gv * (acc[mi][ni][rg] + be[col]);
                }
            }
        }
    }
}

// ---------------- launch ----------------

extern "C" void kernel_launch(void* const* d_in, const int* in_sizes, int n_in,
                              void* d_out, int out_size, void* d_ws, size_t ws_size,
                              hipStream_t stream) {
    const float* x   = (const float*)d_in[0];
    const float* rw  = (const float*)d_in[1];
    const float* w1  = (const float*)d_in[2];
    const float* b1  = (const float*)d_in[3];
    const float* w2  = (const float*)d_in[4];
    const float* b2  = (const float*)d_in[5];
    float* out = (float*)d_out;

    const size_t HCAP = (size_t)PCAP_ * F_;     // 37.7M shorts
    const size_t XCAP = (size_t)PCAP_ * D_;     // 9.4M shorts
    const size_t WCAP = (size_t)E_ * D_ * F_;   // 16.78M shorts
    const size_t misc = ((size_t)T_ * E_ + T_ + (size_t)E_ * T_) * 4 + 256;
    const size_t need = (HCAP + XCAP + WCAP) * 2 + misc;   // ~128 MB

    if (ws_size < need) return;  // fail loudly

    ushort_t* hB = (ushort_t*)d_ws;
    ushort_t* xB = hB + HCAP;
    ushort_t* wB = xB + XCAP;
    float* r    = (float*)(wB + WCAP);
    float* gate = r + (size_t)T_ * E_;
    int* list   = (int*)(gate + T_);
    int* counts = list + (size_t)E_ * T_;
    int* offs   = counts + E_;
    int* pbase  = offs + E_;

    k_router<<<T_ / 4, 256, 0, stream>>>(x, rw, r, counts);
    k_convert_w1<<<dim3(F_ / 128, D_ / 32, E_), 256, 0, stream>>>(w1, wB, D_, F_);
    k_scan<<<B_ * E_, 64, 0, stream>>>(r);
    k_route<<<T_ / 256, 256, 0, stream>>>(r, gate, list, counts);
    k_offs<<<1, 64, 0, stream>>>(counts, offs, pbase);
    k_gather1<<<GCAP_, 256, 0, stream>>>(x, list, counts, pbase, xB);

    k_gA<0><<<dim3(T_ / 256, F_ / 256, E_), 512, 0, stream>>>(
        xB, wB, b1, nullptr, hB, list, counts, pbase, nullptr);
    k_convert_w1<<<dim3(D_ / 128, F_ / 32, E_), 256, 0, stream>>>(w2, wB, F_, D_);
    k_gA<1><<<dim3(T_ / 256, D_ / 128, E_), 512, 0, stream>>>(
        hB, wB, b2, out, nullptr, list, counts, pbase, gate);
}

// Round 11
// 503.743 us; speedup vs baseline: 2.0908x; 1.4127x over previous
//
#include <hip/hip_runtime.h>
#include <math.h>

#define B_ 4
#define S_ 2048
#define D_ 1024
#define F_ 4096
#define E_ 4
#define T_ (B_*S_)        // 8192 tokens
#define PCAP_ 9216        // max padded rows (256-pad per expert)
#define GCAP_ (PCAP_/16)  // 576 row-groups
#define MBMAX_ (PCAP_/256) // 36 global m-blocks

typedef unsigned short ushort_t;
typedef __attribute__((ext_vector_type(8))) short short8;
typedef __attribute__((ext_vector_type(4))) float f32x4;

__device__ __forceinline__ ushort_t f2bf_rne(float f) {
    unsigned u = __float_as_uint(f);
    unsigned r = 0x7FFFu + ((u >> 16) & 1u);
    u += r;
    return (ushort_t)(u >> 16);
}

__device__ __forceinline__ void gload16(const void* g, void* l) {
    __builtin_amdgcn_global_load_lds(
        (const __attribute__((address_space(1))) unsigned int*)g,
        (__attribute__((address_space(3))) unsigned int*)l, 16, 0, 0);
}

// ---------------- routing ----------------

__global__ void k_router(const float* __restrict__ x, const float* __restrict__ rw,
                         float* __restrict__ r, int* __restrict__ counts) {
    if (blockIdx.x == 0 && threadIdx.x < E_) counts[threadIdx.x] = 0;
    int wid = blockIdx.x * 4 + (threadIdx.x >> 6);
    int lane = threadIdx.x & 63;
    const float* xr = x + (size_t)wid * D_;
    float a0 = 0.f, a1 = 0.f, a2 = 0.f, a3 = 0.f;
    for (int i = lane; i < D_; i += 64) {
        float xv = xr[i];
        float4 w = reinterpret_cast<const float4*>(rw)[i];
        a0 += xv * w.x; a1 += xv * w.y; a2 += xv * w.z; a3 += xv * w.w;
    }
    for (int off = 32; off; off >>= 1) {
        a0 += __shfl_down(a0, off, 64);
        a1 += __shfl_down(a1, off, 64);
        a2 += __shfl_down(a2, off, 64);
        a3 += __shfl_down(a3, off, 64);
    }
    if (lane == 0) {
        float4 v; v.x = a0; v.y = a1; v.z = a2; v.w = a3;
        reinterpret_cast<float4*>(r)[wid] = v;
    }
}

__global__ void k_scan(float* __restrict__ r) {
    int b = blockIdx.x >> 2, e = blockIdx.x & 3;
    int lane = threadIdx.x;
    float carry = 0.f;
    for (int c = 0; c < S_ / 64; ++c) {
        int s = c * 64 + lane;
        float* p = r + ((size_t)(b * S_ + s)) * E_ + e;
        float v = *p;
        #pragma unroll
        for (int off = 1; off < 64; off <<= 1) {
            float u = __shfl_up(v, off, 64);
            if (lane >= off) v += u;
        }
        v += carry;
        *p = v;
        carry = __shfl(v, 63, 64);
    }
}

__global__ void k_route(const float* __restrict__ r, float* __restrict__ gate,
                        int* __restrict__ list, int* __restrict__ counts) {
    int t = blockIdx.x * blockDim.x + threadIdx.x;
    if (t >= T_) return;
    int s = t & (S_ - 1);
    float4 l4 = reinterpret_cast<const float4*>(r)[t];
    float inv = 1.f / (float)(s + 1);
    float l[4] = { l4.x * inv, l4.y * inv, l4.z * inv, l4.w * inv };
    int best = 0; float m = l[0];
    #pragma unroll
    for (int e = 1; e < 4; ++e) if (l[e] > m) { m = l[e]; best = e; }
    float sum = 0.f;
    #pragma unroll
    for (int e = 0; e < 4; ++e) sum += expf(l[e] - m);
    gate[t] = 1.f / sum;
    int pos = atomicAdd(&counts[best], 1);
    list[best * T_ + pos] = t;
}

__global__ void k_offs(const int* __restrict__ counts, int* __restrict__ offs,
                       int* __restrict__ pbase) {
    if (threadIdx.x == 0) {
        int a = 0, p = 0;
        pbase[0] = 0;
        for (int e = 0; e < E_; ++e) {
            offs[e] = a; a += counts[e];
            p += (counts[e] + 255) & ~255;   // 256-row padding (tile = 256 rows)
            pbase[e + 1] = p;
        }
    }
}

// ---------------- gather x into padded expert order, frag-tiled bf16 ----------------
// Plane layout: [g16][kb=K/32][lane64=kg*16+r15][8], elem k = kb*32+kg*8+j.
__global__ __launch_bounds__(256)
void k_gather1(const float* __restrict__ x, const int* __restrict__ list,
               const int* __restrict__ counts, const int* __restrict__ pbase,
               ushort_t* __restrict__ Xb)
{
    constexpr int KB = D_ / 32;
    const int g = blockIdx.x;
    const int r15 = threadIdx.x & 15;
    const int kq = threadIdx.x >> 4;
    const int v = g * 16 + r15;
    int e = 0;
    #pragma unroll
    for (int i = 0; i < E_; ++i) if (v >= pbase[i + 1]) e = i + 1;
    int token = -1;
    if (e < E_) {
        int local = v - pbase[e];
        if (local < counts[e]) token = list[e * T_ + local];
    }
    const float* xr = x + (size_t)(token >= 0 ? token : 0) * D_;
    #pragma unroll
    for (int c8 = 0; c8 < 8; ++c8) {
        const int k = kq * 64 + c8 * 8;
        float vv[8];
        if (token >= 0) {
            float4 u0 = *reinterpret_cast<const float4*>(xr + k);
            float4 u1 = *reinterpret_cast<const float4*>(xr + k + 4);
            vv[0]=u0.x; vv[1]=u0.y; vv[2]=u0.z; vv[3]=u0.w;
            vv[4]=u1.x; vv[5]=u1.y; vv[6]=u1.z; vv[7]=u1.w;
        } else {
            #pragma unroll
            for (int j = 0; j < 8; ++j) vv[j] = 0.f;
        }
        unsigned hw[4];
        #pragma unroll
        for (int j = 0; j < 4; ++j)
            hw[j] = (unsigned)f2bf_rne(vv[2*j]) | ((unsigned)f2bf_rne(vv[2*j+1]) << 16);
        size_t off = (((size_t)g * KB + (k >> 5)) * 64 + ((k >> 3) & 3) * 16 + r15) * 8;
        *reinterpret_cast<uint4*>(Xb + off) = make_uint4(hw[0], hw[1], hw[2], hw[3]);
    }
}

// ---------------- weight conversion to frag-order bf16 plane ----------------
__global__ __launch_bounds__(256)
void k_convert_w1(const float* __restrict__ W, ushort_t* __restrict__ P,
                  int K, int N) {
    const int e = blockIdx.z;
    const int n0 = blockIdx.x * 128;
    const int k0 = blockIdx.y * 32;
    const int kb = blockIdx.y;
    const int NT = N >> 4, KB = K >> 5;
    __shared__ float lf[32 * 128];
    const float* We = W + (size_t)e * K * N;
    const int tid = threadIdx.x;
    #pragma unroll
    for (int i = 0; i < 4; ++i) {
        int q = i * 256 + tid;
        int k = q >> 5, c4 = q & 31;
        float4 v = *reinterpret_cast<const float4*>(We + (size_t)(k0 + k) * N + n0 + c4 * 4);
        *reinterpret_cast<float4*>(lf + k * 128 + c4 * 4) = v;
    }
    __syncthreads();
    #pragma unroll
    for (int p = 0; p < 2; ++p) {
        int q = p * 256 + tid;
        int n = q & 127, kg = q >> 7;
        unsigned hw[4];
        #pragma unroll
        for (int j = 0; j < 8; j += 2) {
            float f0 = lf[(kg * 8 + j) * 128 + n];
            float f1 = lf[(kg * 8 + j + 1) * 128 + n];
            hw[j >> 1] = (unsigned)f2bf_rne(f0) | ((unsigned)f2bf_rne(f1) << 16);
        }
        size_t off = ((((size_t)e * NT + ((n0 + n) >> 4)) * KB + kb) * 64
                      + (kg * 16 + (n & 15))) * 8;
        *reinterpret_cast<uint4*>(P + off) = make_uint4(hw[0], hw[1], hw[2], hw[3]);
    }
}

// ---------------- main grouped GEMMs: compact-grid 256-tile 2-phase ----------------
// MODE 0: h(frag bf16) = gelu(Xg @ w1 + b1)  K=1024, BN=256, grid (36, 16)
// MODE 1: out += gate*(h @ w2 [+ b2])        K=4096 split 2x2048, BN=128,
//         grid (36, 8, 2), atomicAdd epilogue into zeroed out.
// 8 waves. Block tile 256(M) x BN. Wave grid 2Mx4N. One barrier/step 2-phase.
template<int MODE>
__global__ __launch_bounds__(512)
void k_gB(const ushort_t* __restrict__ A, const ushort_t* __restrict__ Bw,
          const float* __restrict__ bias, float* __restrict__ outF,
          ushort_t* __restrict__ outH,
          const int* __restrict__ list, const int* __restrict__ counts,
          const int* __restrict__ pbase, const float* __restrict__ gate)
{
    constexpr int K    = (MODE == 0) ? D_ : F_;
    constexpr int N    = (MODE == 0) ? F_ : D_;
    constexpr int BN   = (MODE == 0) ? 256 : 128;
    constexpr int NI   = BN / 64;            // 4 or 2
    constexpr int KSEG = (MODE == 0) ? K : K / 2;   // per-block K range
    constexpr int STEPS = KSEG / 64;         // 16 or 32
    constexpr int KB32 = K / 32;
    constexpr int NT   = N / 16;
    constexpr int KBH  = F_ / 32;
    constexpr int ACH  = 32;                 // A chunks of 1KB per step
    constexpr int BCH  = (BN / 16) * 2;      // 32 or 16
    constexpr int BPW  = BCH / 8;            // 4 or 2
    constexpr int LSZ  = (ACH + BCH) * 512;

    // compact m-block -> (expert, m0)
    const int m0g = blockIdx.x * 256;
    if (m0g >= pbase[E_]) return;
    int e = 0;
    #pragma unroll
    for (int i = 1; i <= 3; ++i) if (m0g >= pbase[i]) e = i;
    const int cnt = counts[e];
    const int m0 = m0g - pbase[e];
    if (m0 >= cnt) return;                   // pure-pad block
    const int n0 = blockIdx.y * BN;
    const int kth = (MODE == 0) ? 0 : blockIdx.z;
    const int koff = kth * (KSEG / 32);      // kb offset of this K-segment

    const int tid = threadIdx.x, wid = tid >> 6, lane = tid & 63;
    const int l15 = lane & 15, lkg = lane >> 4;
    const int wr = wid >> 2, wc = wid & 3;
    const int G0 = m0g >> 4;

    __shared__ __align__(16) ushort_t lds[2][LSZ];

    const ushort_t* aP[4];
    #pragma unroll
    for (int j = 0; j < 4; ++j) {
        const int c = wid * 4 + j;
        aP[j] = A + ((size_t)(G0 + (c >> 1)) * KB32 + (c & 1) + koff) * 512
                  + (size_t)lane * 8;
    }
    const ushort_t* bP[BPW];
    #pragma unroll
    for (int j = 0; j < BPW; ++j) {
        const int c = wid * BPW + j;
        bP[j] = Bw + (((size_t)e * NT + (n0 >> 4) + (c >> 1)) * KB32 + (c & 1) + koff) * 512
                   + (size_t)lane * 8;
    }

    f32x4 acc[8][NI];
    #pragma unroll
    for (int i = 0; i < 8; ++i)
        #pragma unroll
        for (int j = 0; j < NI; ++j) acc[i][j] = (f32x4){0.f, 0.f, 0.f, 0.f};

    // ---- prologue: stage tile 0 into buf 0 ----
    #pragma unroll
    for (int j = 0; j < 4; ++j)
        gload16(aP[j], &lds[0][(wid * 4 + j) * 512]);
    #pragma unroll
    for (int j = 0; j < BPW; ++j)
        gload16(bP[j], &lds[0][(ACH + wid * BPW + j) * 512]);
    __syncthreads();

    int cur = 0;
    for (int t = 0; t < STEPS; ++t) {
        if (t + 1 < STEPS) {
            const size_t so = (size_t)(t + 1) * 1024;
            ushort_t* L = &lds[cur ^ 1][0];
            #pragma unroll
            for (int j = 0; j < 4; ++j)
                gload16(aP[j] + so, L + (wid * 4 + j) * 512);
            #pragma unroll
            for (int j = 0; j < BPW; ++j)
                gload16(bP[j] + so, L + (ACH + wid * BPW + j) * 512);
        }
        const ushort_t* L = &lds[cur][0];
        __builtin_amdgcn_s_setprio(1);
        #pragma unroll
        for (int kk = 0; kk < 2; ++kk) {
            short8 av[8];
            #pragma unroll
            for (int mi = 0; mi < 8; ++mi)
                av[mi] = *reinterpret_cast<const short8*>(
                    &L[((wr * 8 + mi) * 2 + kk) * 512 + lane * 8]);
            short8 bv[NI];
            #pragma unroll
            for (int ni = 0; ni < NI; ++ni)
                bv[ni] = *reinterpret_cast<const short8*>(
                    &L[(ACH + (wc * NI + ni) * 2 + kk) * 512 + lane * 8]);
            #pragma unroll
            for (int mi = 0; mi < 8; ++mi)
                #pragma unroll
                for (int ni = 0; ni < NI; ++ni)
                    acc[mi][ni] = __builtin_amdgcn_mfma_f32_16x16x32_bf16(
                        av[mi], bv[ni], acc[mi][ni], 0, 0, 0);
        }
        __builtin_amdgcn_s_setprio(0);
        __syncthreads();
        cur ^= 1;
    }

    const float* be = bias + (size_t)e * N;
    if (MODE == 0) {
        #pragma unroll
        for (int mi = 0; mi < 8; ++mi) {
            const int g2 = G0 + wr * 8 + mi;
            #pragma unroll
            for (int rg = 0; rg < 4; ++rg) {
                const int r15o = lkg * 4 + rg;
                #pragma unroll
                for (int ni = 0; ni < NI; ++ni) {
                    const int f = n0 + wc * 64 + ni * 16 + l15;
                    float v = acc[mi][ni][rg] + be[f];
                    float u = 1.5957691216057308f * (v + 0.044715f * v * v * v);
                    v = v / (1.f + __expf(-u));
                    size_t off = (((size_t)g2 * KBH + (f >> 5)) * 64
                                  + ((f >> 3) & 3) * 16 + r15o) * 8 + (f & 7);
                    outH[off] = f2bf_rne(v);
                }
            }
        }
    } else {
        const int* lst = list + (size_t)e * T_;
        #pragma unroll
        for (int mi = 0; mi < 8; ++mi) {
            #pragma unroll
            for (int rg = 0; rg < 4; ++rg) {
                int rm = m0 + wr * 128 + mi * 16 + lkg * 4 + rg;
                if (rm >= cnt) continue;
                int t = lst[rm];
                float gv = gate[t];
                float* crow = outF + (size_t)t * (size_t)N;
                #pragma unroll
                for (int ni = 0; ni < NI; ++ni) {
                    int col = n0 + wc * 32 + ni * 16 + l15;
                    float v = acc[mi][ni][rg] + (kth == 0 ? be[col] : 0.f);
                    atomicAdd(&crow[col], gv * v);
                }
            }
        }
    }
}

// ---------------- launch ----------------

extern "C" void kernel_launch(void* const* d_in, const int* in_sizes, int n_in,
                              void* d_out, int out_size, void* d_ws, size_t ws_size,
                              hipStream_t stream) {
    const float* x   = (const float*)d_in[0];
    const float* rw  = (const float*)d_in[1];
    const float* w1  = (const float*)d_in[2];
    const float* b1  = (const float*)d_in[3];
    const float* w2  = (const float*)d_in[4];
    const float* b2  = (const float*)d_in[5];
    float* out = (float*)d_out;

    const size_t HCAP = (size_t)PCAP_ * F_;     // 37.7M shorts
    const size_t XCAP = (size_t)PCAP_ * D_;     // 9.4M shorts
    const size_t WCAP = (size_t)E_ * D_ * F_;   // 16.78M shorts
    const size_t misc = ((size_t)T_ * E_ + T_ + (size_t)E_ * T_) * 4 + 256;
    const size_t need = (HCAP + XCAP + WCAP) * 2 + misc;   // ~128 MB

    if (ws_size < need) return;  // fail loudly

    ushort_t* hB = (ushort_t*)d_ws;
    ushort_t* xB = hB + HCAP;
    ushort_t* wB = xB + XCAP;
    float* r    = (float*)(wB + WCAP);
    float* gate = r + (size_t)T_ * E_;
    int* list   = (int*)(gate + T_);
    int* counts = list + (size_t)E_ * T_;
    int* offs   = counts + E_;
    int* pbase  = offs + E_;

    hipMemsetAsync(out, 0, (size_t)T_ * D_ * 4, stream);   // atomic-add target

    k_router<<<T_ / 4, 256, 0, stream>>>(x, rw, r, counts);
    k_convert_w1<<<dim3(F_ / 128, D_ / 32, E_), 256, 0, stream>>>(w1, wB, D_, F_);
    k_scan<<<B_ * E_, 64, 0, stream>>>(r);
    k_route<<<T_ / 256, 256, 0, stream>>>(r, gate, list, counts);
    k_offs<<<1, 64, 0, stream>>>(counts, offs, pbase);
    k_gather1<<<GCAP_, 256, 0, stream>>>(x, list, counts, pbase, xB);

    k_gB<0><<<dim3(MBMAX_, F_ / 256), 512, 0, stream>>>(
        xB, wB, b1, nullptr, hB, list, counts, pbase, nullptr);
    k_convert_w1<<<dim3(D_ / 128, F_ / 32, E_), 256, 0, stream>>>(w2, wB, F_, D_);
    k_gB<1><<<dim3(MBMAX_, D_ / 128, 2), 512, 0, stream>>>(
        hB, wB, b2, out, nullptr, list, counts, pbase, gate);
}